// Round 10
// baseline (583.563 us; speedup 1.0000x reference)
//
#include <hip/hip_runtime.h>
#include <math.h>

#define N_NODES 50000
#define E_ORIG  800000
#define E_TOT   850000   // + self loops
#define SNB     49       // scan blocks: 49 * 1024 >= N_NODES
#define BPG     782      // gather node-blocks per slice: 782 * 64 >= N_NODES

typedef __attribute__((ext_vector_type(8))) short short8;   // 8 bf16 (4 VGPRs)
typedef __attribute__((ext_vector_type(4))) float f32x4;    // MFMA acc

__device__ __forceinline__ short f2bf(float f) {            // fp32 -> bf16 RNE
    unsigned u = __builtin_bit_cast(unsigned, f);
    u += 0x7FFFu + ((u >> 16) & 1u);
    return (short)(u >> 16);
}
__device__ __forceinline__ float bf2f(short s) {
    unsigned u = ((unsigned)(unsigned short)s) << 16;
    return __builtin_bit_cast(float, u);
}

// ---------------- bf16 MFMA GEMM: C_t[blk][m][32] = (A[M,K] @ W[K,N]) sliced ----------------
__global__ __launch_bounds__(256) void gemm_bf16(const short* __restrict__ A,
                                                 const short* __restrict__ Wt,   // W^T [N][K]
                                                 short* __restrict__ C,          // [N/32][N_NODES][32]
                                                 int M, int N, int K)
{
    __shared__ short sA[128][40];
    __shared__ short sB[64][40];
    const int t    = threadIdx.x;
    const int wave = t >> 6, lane = t & 63;
    const int quad = lane >> 4, mrow = lane & 15;
    const int m0 = blockIdx.y * 128, n0 = blockIdx.x * 64;
    const int wm = (wave & 1) * 64, wn = (wave >> 1) * 32;

    f32x4 acc[4][2] = {};

    const int ra = t >> 2, ka = (t & 3) << 3;
    const int rb = t >> 2, kb = (t & 3) << 3;

    for (int k0 = 0; k0 < K; k0 += 32) {
#pragma unroll
        for (int rr = 0; rr < 2; ++rr) {
            int row = ra + rr * 64;
            int gm = m0 + row;
            int4 v = {0, 0, 0, 0};
            if (gm < M) v = *(const int4*)(A + (size_t)gm * K + k0 + ka);
            *(int4*)&sA[row][ka] = v;
        }
        {
            int4 v = *(const int4*)(Wt + (size_t)(n0 + rb) * K + k0 + kb);
            *(int4*)&sB[rb][kb] = v;
        }
        __syncthreads();
        short8 af[4], bfr[2];
#pragma unroll
        for (int mi = 0; mi < 4; ++mi)
            af[mi] = *(const short8*)&sA[wm + mi * 16 + mrow][quad * 8];
#pragma unroll
        for (int ni = 0; ni < 2; ++ni)
            bfr[ni] = *(const short8*)&sB[wn + ni * 16 + mrow][quad * 8];
#pragma unroll
        for (int mi = 0; mi < 4; ++mi)
#pragma unroll
            for (int ni = 0; ni < 2; ++ni)
                acc[mi][ni] = __builtin_amdgcn_mfma_f32_16x16x32_bf16(af[mi], bfr[ni], acc[mi][ni], 0, 0, 0);
        __syncthreads();
    }
    // C/D layout: col = lane&15, row = quad*4 + reg; write slice-major
#pragma unroll
    for (int mi = 0; mi < 4; ++mi) {
#pragma unroll
        for (int ni = 0; ni < 2; ++ni) {
            int gn = n0 + wn + ni * 16 + mrow;
            size_t sbase = ((size_t)(gn >> 5) * N_NODES) * 32 + (gn & 31);
            int gmb = m0 + wm + mi * 16 + quad * 4;
#pragma unroll
            for (int r = 0; r < 4; ++r) {
                int gm = gmb + r;
                if (gm < M) C[sbase + (size_t)gm * 32] = f2bf(acc[mi][ni][r]);
            }
        }
    }
}

// ---------------- casts ----------------
__global__ void xcast_kernel(const float* __restrict__ x, short* __restrict__ xb, int total4)
{
    int i = blockIdx.x * blockDim.x + threadIdx.x;
    if (i >= total4) return;
    float4 v = ((const float4*)x)[i];
    short4 o; o.x = f2bf(v.x); o.y = f2bf(v.y); o.z = f2bf(v.z); o.w = f2bf(v.w);
    ((short4*)xb)[i] = o;
}

__global__ void wtcast_all(const float* __restrict__ W1, const float* __restrict__ W2,
                           const float* __restrict__ W3, short* __restrict__ wt)
{
    int i = blockIdx.x * blockDim.x + threadIdx.x;
    if (i < 32768) {                       // W1: K=128, N=256
        int n = i / 128, k = i % 128;
        wt[i] = f2bf(W1[(size_t)k * 256 + n]);
    } else if (i < 98304) {                // W2: K=256, N=256
        int j = i - 32768;
        int n = j / 256, k = j % 256;
        wt[i] = f2bf(W2[(size_t)k * 256 + n]);
    } else if (i < 131072) {               // W3: K=256, N=128
        int j = i - 98304;
        int n = j / 256, k = j % 256;
        wt[i] = f2bf(W3[(size_t)k * 128 + n]);
    }
}

// ---------------- attention logits, head-major outputs: al[h][n] ----------------
template<int H, int BPH>
__global__ void logits_blk(const short* __restrict__ ht,
                           const float* __restrict__ a_src,
                           const float* __restrict__ a_dst,
                           float* __restrict__ al_s, float* __restrict__ al_d)
{
    int i = blockIdx.x * blockDim.x + threadIdx.x;
    if (i >= N_NODES * H) return;
    int n = i / H, hh = i % H;
    float ss = 0.f, sd = 0.f;
#pragma unroll
    for (int b = 0; b < BPH; ++b) {
        int blk = hh * BPH + b;
        const short* hp = ht + ((size_t)blk * N_NODES + n) * 32;
        const float* as = a_src + blk * 32;
        const float* ad = a_dst + blk * 32;
#pragma unroll
        for (int c8 = 0; c8 < 32; c8 += 8) {
            short8 hv = *(const short8*)(hp + c8);
#pragma unroll
            for (int j = 0; j < 8; ++j) {
                float v = bf2f(hv[j]);
                ss = fmaf(v, as[c8 + j], ss);
                sd = fmaf(v, ad[c8 + j], sd);
            }
        }
    }
    al_s[(size_t)hh * N_NODES + n] = ss;
    al_d[(size_t)hh * N_NODES + n] = sd;
}

// ---------------- CSR build ----------------
__global__ void deg_kernel(const int* __restrict__ ei, int* __restrict__ deg)
{
    int e = blockIdx.x * blockDim.x + threadIdx.x;
    if (e >= E_TOT) return;
    int d = (e < E_ORIG) ? ei[E_ORIG + e] : e - E_ORIG;
    atomicAdd(&deg[d], 1);
}

__global__ __launch_bounds__(256) void scan_p1(const int* __restrict__ deg, int* __restrict__ bsum)
{
    __shared__ int wsum[4];
    int t = threadIdx.x;
    int base = blockIdx.x * 1024 + t * 4;
    int s = 0;
    if (base + 3 < N_NODES) {
        int4 v = *(const int4*)(deg + base);
        s = v.x + v.y + v.z + v.w;
    } else if (base < N_NODES) {
        for (int j = 0; j < 4 && base + j < N_NODES; ++j) s += deg[base + j];
    }
#pragma unroll
    for (int d = 32; d; d >>= 1) s += __shfl_down(s, d);
    if ((t & 63) == 0) wsum[t >> 6] = s;
    __syncthreads();
    if (t == 0) bsum[blockIdx.x] = wsum[0] + wsum[1] + wsum[2] + wsum[3];
}

__global__ void scan_p2(const int* __restrict__ bsum, int* __restrict__ bpre,
                        int* __restrict__ row_ptr)
{
    int t = threadIdx.x;   // 64 threads
    int v = (t < SNB) ? bsum[t] : 0;
    int inc = v;
#pragma unroll
    for (int d = 1; d < 64; d <<= 1) {
        int u = __shfl_up(inc, d);
        if (t >= d) inc += u;
    }
    if (t < SNB) bpre[t] = inc - v;
    if (t == SNB - 1) row_ptr[N_NODES] = inc;
}

__global__ __launch_bounds__(256) void scan_p3(const int* __restrict__ deg,
                                               const int* __restrict__ bpre,
                                               int* __restrict__ row_ptr,
                                               int* __restrict__ cursor)
{
    __shared__ int tsum[256];
    int t = threadIdx.x;
    int base = blockIdx.x * 1024 + t * 4;
    int d0 = 0, d1 = 0, d2 = 0, d3 = 0;
    if (base + 3 < N_NODES) {
        int4 v = *(const int4*)(deg + base);
        d0 = v.x; d1 = v.y; d2 = v.z; d3 = v.w;
    } else if (base < N_NODES) {
        d0 = deg[base];
        if (base + 1 < N_NODES) d1 = deg[base + 1];
        if (base + 2 < N_NODES) d2 = deg[base + 2];
    }
    int s = d0 + d1 + d2 + d3;
    tsum[t] = s;
    __syncthreads();
    for (int off = 1; off < 256; off <<= 1) {
        int u = (t >= off) ? tsum[t - off] : 0;
        __syncthreads();
        tsum[t] += u;
        __syncthreads();
    }
    int run = bpre[blockIdx.x] + tsum[t] - s;
    if (base < N_NODES)     { row_ptr[base]     = run; cursor[base]     = run; run += d0; }
    if (base + 1 < N_NODES) { row_ptr[base + 1] = run; cursor[base + 1] = run; run += d1; }
    if (base + 2 < N_NODES) { row_ptr[base + 2] = run; cursor[base + 2] = run; run += d2; }
    if (base + 3 < N_NODES) { row_ptr[base + 3] = run; cursor[base + 3] = run; }
}

__global__ void fill_kernel(const int* __restrict__ ei, int* __restrict__ cursor,
                            int* __restrict__ col, int* __restrict__ dstv)
{
    int e = blockIdx.x * blockDim.x + threadIdx.x;
    if (e >= E_TOT) return;
    int s, d;
    if (e < E_ORIG) { s = ei[e]; d = ei[E_ORIG + e]; } else { s = d = e - E_ORIG; }
    int pos = atomicAdd(&cursor[d], 1);
    col[pos] = s;
    dstv[pos] = d;
}

// ---------------- unnormalized edge weights, head-major: w[h][e] ----------------
template<int H>
__global__ void edge_w_kernel(const int* __restrict__ col, const int* __restrict__ dstv,
                              const float* __restrict__ al_s, const float* __restrict__ al_d,
                              float* __restrict__ w)
{
    int e = blockIdx.x * blockDim.x + threadIdx.x;
    if (e >= E_TOT) return;
    int s = col[e], d = dstv[e];
#pragma unroll
    for (int h = 0; h < H; ++h) {
        float v = al_s[(size_t)h * N_NODES + s] + al_d[(size_t)h * N_NODES + d];
        v = v > 0.f ? v : 0.2f * v;
        w[(size_t)h * E_TOT + e] = __expf(v);
    }
}

// ---------------- slice-blocked gather, XCD-pinned, 4 lanes x short8 per edge ----------------
// slice = blockIdx.x % NBLK (-> XCD via round-robin dispatch), node-range = blockIdx.x / NBLK.
// Each XCD's L2 holds only its 3.2 MB slice + 3.4 MB w-head stream. 16 B h-load per lane.
template<int HC, int H, bool BN, bool OUTBF>
__global__ __launch_bounds__(256) void gat_gather_blk(const int* __restrict__ row_ptr,
                                                      const int* __restrict__ col,
                                                      const short* __restrict__ ht,
                                                      const float* __restrict__ wv,   // [h][e]
                                                      const float* __restrict__ bias,
                                                      const float* __restrict__ gamma,
                                                      const float* __restrict__ beta,
                                                      const float* __restrict__ mean,
                                                      const float* __restrict__ var,
                                                      void* __restrict__ outp)
{
    constexpr int NBLK = HC / 32;
    int blk  = blockIdx.x % NBLK;        // slice id == XCD id (mod 8)
    int nb   = blockIdx.x / NBLK;
    int n = nb * 64 + (threadIdx.x >> 2);
    if (n >= N_NODES) return;
    int lane  = threadIdx.x & 3;
    int head  = (blk * H) / NBLK;
    int c_loc = lane * 8;
    const short* hb = ht + (size_t)blk * N_NODES * 32 + c_loc;
    const float* wh = wv + (size_t)head * E_TOT;
    int beg = row_ptr[n], end = row_ptr[n + 1];
    float a0 = 0.f, a1 = 0.f, a2 = 0.f, a3 = 0.f;
    float a4 = 0.f, a5 = 0.f, a6 = 0.f, a7 = 0.f, den = 0.f;
#define ACC(hv, w) { \
        a0 = fmaf(w, bf2f(hv[0]), a0); a1 = fmaf(w, bf2f(hv[1]), a1); \
        a2 = fmaf(w, bf2f(hv[2]), a2); a3 = fmaf(w, bf2f(hv[3]), a3); \
        a4 = fmaf(w, bf2f(hv[4]), a4); a5 = fmaf(w, bf2f(hv[5]), a5); \
        a6 = fmaf(w, bf2f(hv[6]), a6); a7 = fmaf(w, bf2f(hv[7]), a7); }
    int e = beg;
    for (; e + 3 < end; e += 4) {
        int s0 = col[e], s1 = col[e + 1], s2 = col[e + 2], s3 = col[e + 3];
        float w0 = wh[e], w1 = wh[e + 1], w2 = wh[e + 2], w3 = wh[e + 3];
        short8 h0 = *(const short8*)(hb + (size_t)s0 * 32);
        short8 h1 = *(const short8*)(hb + (size_t)s1 * 32);
        short8 h2 = *(const short8*)(hb + (size_t)s2 * 32);
        short8 h3 = *(const short8*)(hb + (size_t)s3 * 32);
        den += (w0 + w1) + (w2 + w3);
        ACC(h0, w0); ACC(h1, w1); ACC(h2, w2); ACC(h3, w3);
    }
    for (; e < end; ++e) {
        int s0 = col[e];
        float w0 = wh[e];
        short8 h0 = *(const short8*)(hb + (size_t)s0 * 32);
        den += w0;
        ACC(h0, w0);
    }
#undef ACC
    float inv = 1.f / den;
    float r[8] = { a0 * inv, a1 * inv, a2 * inv, a3 * inv,
                   a4 * inv, a5 * inv, a6 * inv, a7 * inv };
    int cb = blk * 32 + c_loc;
#pragma unroll
    for (int j = 0; j < 8; ++j) {
        int c = cb + j;
        float v = r[j] + bias[c];
        if (BN) {
            v = (v - mean[c]) * rsqrtf(var[c] + 1e-5f) * gamma[c] + beta[c];
            v = v > 0.f ? v : expm1f(v);   // ELU
        }
        r[j] = v;
    }
    if (OUTBF) {
        short8 o;
#pragma unroll
        for (int j = 0; j < 8; ++j) o[j] = f2bf(r[j]);
        *(short8*)((short*)outp + (size_t)n * HC + cb) = o;
    } else {
        float* op = (float*)outp + (size_t)n * HC + cb;
        *(float4*)op       = make_float4(r[0], r[1], r[2], r[3]);
        *(float4*)(op + 4) = make_float4(r[4], r[5], r[6], r[7]);
    }
}

extern "C" void kernel_launch(void* const* d_in, const int* in_sizes, int n_in,
                              void* d_out, int out_size, void* d_ws, size_t ws_size,
                              hipStream_t stream)
{
    const float* x   = (const float*)d_in[0];
    const int*   ei  = (const int*)d_in[1];
    const float* W1  = (const float*)d_in[2];
    const float* as1 = (const float*)d_in[3];
    const float* ad1 = (const float*)d_in[4];
    const float* b1  = (const float*)d_in[5];
    const float* g1  = (const float*)d_in[6];
    const float* be1 = (const float*)d_in[7];
    const float* mn1 = (const float*)d_in[8];
    const float* vr1 = (const float*)d_in[9];
    const float* W2  = (const float*)d_in[10];
    const float* as2 = (const float*)d_in[11];
    const float* ad2 = (const float*)d_in[12];
    const float* b2  = (const float*)d_in[13];
    const float* g2  = (const float*)d_in[14];
    const float* be2 = (const float*)d_in[15];
    const float* mn2 = (const float*)d_in[16];
    const float* vr2 = (const float*)d_in[17];
    const float* W3  = (const float*)d_in[18];
    const float* as3 = (const float*)d_in[19];
    const float* ad3 = (const float*)d_in[20];
    const float* b3  = (const float*)d_in[21];

    char* p = (char*)d_ws;
    short* hbuf    = (short*)p; p += (size_t)N_NODES * 256 * 2;     // 25.6 MB (slice-major h)
    short* obuf    = (short*)p; p += (size_t)N_NODES * 256 * 2;     // 25.6 MB (row-major layer out)
    short* xbf     = (short*)p; p += (size_t)N_NODES * 128 * 2;     // 12.8 MB (bf16 x)
    float* wbuf    = (float*)p; p += (size_t)E_TOT * 8 * 4;         // 27.2 MB (w[h][e])
    short* wtbuf   = (short*)p; p += (size_t)131072 * 2;            // 256 KB (wt1|wt2|wt3)
    float* als     = (float*)p; p += (size_t)N_NODES * 8 * 4;       // head-major [h][n]
    float* ald     = (float*)p; p += (size_t)N_NODES * 8 * 4;
    int*   row_ptr = (int*)p;   p += (size_t)(N_NODES + 1) * 4;
    int*   col     = (int*)p;   p += (size_t)E_TOT * 4;
    int*   dstv    = (int*)p;   p += (size_t)E_TOT * 4;
    int*   deg     = (int*)p;   p += (size_t)N_NODES * 4;
    int*   cursor  = (int*)p;   p += (size_t)N_NODES * 4;
    int*   bsum    = (int*)p;   p += 64 * 4;
    int*   bpre    = (int*)p;   p += 64 * 4;

    short* wt1 = wtbuf;           // [256][128]
    short* wt2 = wtbuf + 32768;   // [256][256]
    short* wt3 = wtbuf + 98304;   // [128][256]

    float* out = (float*)d_out;

    // ----- CSR build + upfront casts -----
    hipMemsetAsync(deg, 0, (size_t)N_NODES * 4, stream);
    deg_kernel<<<(E_TOT + 255) / 256, 256, 0, stream>>>(ei, deg);
    scan_p1<<<SNB, 256, 0, stream>>>(deg, bsum);
    scan_p2<<<1, 64, 0, stream>>>(bsum, bpre, row_ptr);
    scan_p3<<<SNB, 256, 0, stream>>>(deg, bpre, row_ptr, cursor);
    fill_kernel<<<(E_TOT + 255) / 256, 256, 0, stream>>>(ei, cursor, col, dstv);
    xcast_kernel<<<(N_NODES * 128 / 4 + 255) / 256, 256, 0, stream>>>(x, xbf, N_NODES * 128 / 4);
    wtcast_all<<<(131072 + 255) / 256, 256, 0, stream>>>(W1, W2, W3, wtbuf);

    const int nh8 = N_NODES * 8;

    // ----- layer 1: GAT(128 -> 8x32) + BN + ELU -----
    gemm_bf16<<<dim3(4, (N_NODES + 127) / 128), 256, 0, stream>>>(xbf, wt1, hbuf, N_NODES, 256, 128);
    logits_blk<8, 1><<<(nh8 + 255) / 256, 256, 0, stream>>>(hbuf, as1, ad1, als, ald);
    edge_w_kernel<8><<<(E_TOT + 255) / 256, 256, 0, stream>>>(col, dstv, als, ald, wbuf);
    gat_gather_blk<256, 8, true, true><<<BPG * 8, 256, 0, stream>>>(
        row_ptr, col, hbuf, wbuf, b1, g1, be1, mn1, vr1, obuf);

    // ----- layer 2: GAT(256 -> 8x32) + BN + ELU -----
    gemm_bf16<<<dim3(4, (N_NODES + 127) / 128), 256, 0, stream>>>(obuf, wt2, hbuf, N_NODES, 256, 256);
    logits_blk<8, 1><<<(nh8 + 255) / 256, 256, 0, stream>>>(hbuf, as2, ad2, als, ald);
    edge_w_kernel<8><<<(E_TOT + 255) / 256, 256, 0, stream>>>(col, dstv, als, ald, wbuf);
    gat_gather_blk<256, 8, true, true><<<BPG * 8, 256, 0, stream>>>(
        row_ptr, col, hbuf, wbuf, b2, g2, be2, mn2, vr2, obuf);

    // ----- layer 3: GAT(256 -> 1x128), heads=1 (mean == identity) -----
    gemm_bf16<<<dim3(2, (N_NODES + 127) / 128), 256, 0, stream>>>(obuf, wt3, hbuf, N_NODES, 128, 256);
    logits_blk<1, 4><<<(N_NODES + 255) / 256, 256, 0, stream>>>(hbuf, as3, ad3, als, ald);
    edge_w_kernel<1><<<(E_TOT + 255) / 256, 256, 0, stream>>>(col, dstv, als, ald, wbuf);
    gat_gather_blk<128, 1, false, false><<<BPG * 4, 256, 0, stream>>>(
        row_ptr, col, hbuf, wbuf, b3, nullptr, nullptr, nullptr, nullptr, out);
}

// Round 11
// 548.000 us; speedup vs baseline: 1.0649x; 1.0649x over previous
//
#include <hip/hip_runtime.h>
#include <math.h>

#define N_NODES 50000
#define E_ORIG  800000
#define E_TOT   850000   // + self loops
#define SNB     49       // scan blocks: 49 * 1024 >= N_NODES
#define BPG     782      // gather node-blocks per slice: 782 * 64 >= N_NODES

typedef __attribute__((ext_vector_type(8))) short short8;   // 8 bf16 (4 VGPRs)
typedef __attribute__((ext_vector_type(4))) float f32x4;    // MFMA acc

__device__ __forceinline__ short f2bf(float f) {            // fp32 -> bf16 RNE
    unsigned u = __builtin_bit_cast(unsigned, f);
    u += 0x7FFFu + ((u >> 16) & 1u);
    return (short)(u >> 16);
}
__device__ __forceinline__ float bf2f(short s) {
    unsigned u = ((unsigned)(unsigned short)s) << 16;
    return __builtin_bit_cast(float, u);
}

// ---------------- bf16 MFMA GEMM: C_t[blk][m][32] = (A[M,K] @ W[K,N]) sliced ----------------
// 128x128 tile (minimizes A re-reads on these thin GEMMs), BK=32, 4 waves = 64x64 quadrants.
__global__ __launch_bounds__(256) void gemm_bf16(const short* __restrict__ A,
                                                 const short* __restrict__ Wt,   // W^T [N][K]
                                                 short* __restrict__ C,          // [N/32][N_NODES][32]
                                                 int M, int N, int K)
{
    __shared__ short sA[128][40];
    __shared__ short sB[128][40];
    const int t    = threadIdx.x;
    const int wave = t >> 6, lane = t & 63;
    const int quad = lane >> 4, mrow = lane & 15;
    const int m0 = blockIdx.y * 128, n0 = blockIdx.x * 128;
    const int wm = (wave & 1) * 64, wn = (wave >> 1) * 64;

    f32x4 acc[4][4] = {};

    const int ra = t >> 2, ka = (t & 3) << 3;   // A: 2 passes of 64 rows, 8 shorts each
    const int nb = t >> 1, kb = (t & 1) << 4;   // B: 128 rows, 16 shorts per thread

    for (int k0 = 0; k0 < K; k0 += 32) {
#pragma unroll
        for (int rr = 0; rr < 2; ++rr) {
            int row = ra + rr * 64;
            int gm = m0 + row;
            int4 v = {0, 0, 0, 0};
            if (gm < M) v = *(const int4*)(A + (size_t)gm * K + k0 + ka);
            *(int4*)&sA[row][ka] = v;
        }
        {
            const int4* src = (const int4*)(Wt + (size_t)(n0 + nb) * K + k0 + kb);
            *(int4*)&sB[nb][kb]     = src[0];
            *(int4*)&sB[nb][kb + 8] = src[1];
        }
        __syncthreads();
        short8 af[4], bfr[4];
#pragma unroll
        for (int mi = 0; mi < 4; ++mi)
            af[mi] = *(const short8*)&sA[wm + mi * 16 + mrow][quad * 8];
#pragma unroll
        for (int ni = 0; ni < 4; ++ni)
            bfr[ni] = *(const short8*)&sB[wn + ni * 16 + mrow][quad * 8];
#pragma unroll
        for (int mi = 0; mi < 4; ++mi)
#pragma unroll
            for (int ni = 0; ni < 4; ++ni)
                acc[mi][ni] = __builtin_amdgcn_mfma_f32_16x16x32_bf16(af[mi], bfr[ni], acc[mi][ni], 0, 0, 0);
        __syncthreads();
    }
    // C/D layout: col = lane&15, row = quad*4 + reg; write slice-major
#pragma unroll
    for (int mi = 0; mi < 4; ++mi) {
#pragma unroll
        for (int ni = 0; ni < 4; ++ni) {
            int gn = n0 + wn + ni * 16 + mrow;
            size_t sbase = ((size_t)(gn >> 5) * N_NODES) * 32 + (gn & 31);
            int gmb = m0 + wm + mi * 16 + quad * 4;
#pragma unroll
            for (int r = 0; r < 4; ++r) {
                int gm = gmb + r;
                if (gm < M) C[sbase + (size_t)gm * 32] = f2bf(acc[mi][ni][r]);
            }
        }
    }
}

// ---------------- casts ----------------
__global__ void xcast_kernel(const float* __restrict__ x, short* __restrict__ xb, int total4)
{
    int i = blockIdx.x * blockDim.x + threadIdx.x;
    if (i >= total4) return;
    float4 v = ((const float4*)x)[i];
    short4 o; o.x = f2bf(v.x); o.y = f2bf(v.y); o.z = f2bf(v.z); o.w = f2bf(v.w);
    ((short4*)xb)[i] = o;
}

__global__ void wtcast_all(const float* __restrict__ W1, const float* __restrict__ W2,
                           const float* __restrict__ W3, short* __restrict__ wt)
{
    int i = blockIdx.x * blockDim.x + threadIdx.x;
    if (i < 32768) {                       // W1: K=128, N=256
        int n = i / 128, k = i % 128;
        wt[i] = f2bf(W1[(size_t)k * 256 + n]);
    } else if (i < 98304) {                // W2: K=256, N=256
        int j = i - 32768;
        int n = j / 256, k = j % 256;
        wt[i] = f2bf(W2[(size_t)k * 256 + n]);
    } else if (i < 131072) {               // W3: K=256, N=128
        int j = i - 98304;
        int n = j / 256, k = j % 256;
        wt[i] = f2bf(W3[(size_t)k * 128 + n]);
    }
}

// ---------------- attention logits, head-major outputs: al[h][n] ----------------
template<int H, int BPH>
__global__ void logits_blk(const short* __restrict__ ht,
                           const float* __restrict__ a_src,
                           const float* __restrict__ a_dst,
                           float* __restrict__ al_s, float* __restrict__ al_d)
{
    int i = blockIdx.x * blockDim.x + threadIdx.x;
    if (i >= N_NODES * H) return;
    int n = i / H, hh = i % H;
    float ss = 0.f, sd = 0.f;
#pragma unroll
    for (int b = 0; b < BPH; ++b) {
        int blk = hh * BPH + b;
        const short* hp = ht + ((size_t)blk * N_NODES + n) * 32;
        const float* as = a_src + blk * 32;
        const float* ad = a_dst + blk * 32;
#pragma unroll
        for (int c8 = 0; c8 < 32; c8 += 8) {
            short8 hv = *(const short8*)(hp + c8);
#pragma unroll
            for (int j = 0; j < 8; ++j) {
                float v = bf2f(hv[j]);
                ss = fmaf(v, as[c8 + j], ss);
                sd = fmaf(v, ad[c8 + j], sd);
            }
        }
    }
    al_s[(size_t)hh * N_NODES + n] = ss;
    al_d[(size_t)hh * N_NODES + n] = sd;
}

// ---------------- CSR build ----------------
__global__ void deg_kernel(const int* __restrict__ ei, int* __restrict__ deg)
{
    int e = blockIdx.x * blockDim.x + threadIdx.x;
    if (e >= E_TOT) return;
    int d = (e < E_ORIG) ? ei[E_ORIG + e] : e - E_ORIG;
    atomicAdd(&deg[d], 1);
}

__global__ __launch_bounds__(256) void scan_p1(const int* __restrict__ deg, int* __restrict__ bsum)
{
    __shared__ int wsum[4];
    int t = threadIdx.x;
    int base = blockIdx.x * 1024 + t * 4;
    int s = 0;
    if (base + 3 < N_NODES) {
        int4 v = *(const int4*)(deg + base);
        s = v.x + v.y + v.z + v.w;
    } else if (base < N_NODES) {
        for (int j = 0; j < 4 && base + j < N_NODES; ++j) s += deg[base + j];
    }
#pragma unroll
    for (int d = 32; d; d >>= 1) s += __shfl_down(s, d);
    if ((t & 63) == 0) wsum[t >> 6] = s;
    __syncthreads();
    if (t == 0) bsum[blockIdx.x] = wsum[0] + wsum[1] + wsum[2] + wsum[3];
}

__global__ void scan_p2(const int* __restrict__ bsum, int* __restrict__ bpre,
                        int* __restrict__ row_ptr)
{
    int t = threadIdx.x;   // 64 threads
    int v = (t < SNB) ? bsum[t] : 0;
    int inc = v;
#pragma unroll
    for (int d = 1; d < 64; d <<= 1) {
        int u = __shfl_up(inc, d);
        if (t >= d) inc += u;
    }
    if (t < SNB) bpre[t] = inc - v;
    if (t == SNB - 1) row_ptr[N_NODES] = inc;
}

__global__ __launch_bounds__(256) void scan_p3(const int* __restrict__ deg,
                                               const int* __restrict__ bpre,
                                               int* __restrict__ row_ptr,
                                               int* __restrict__ cursor)
{
    __shared__ int tsum[256];
    int t = threadIdx.x;
    int base = blockIdx.x * 1024 + t * 4;
    int d0 = 0, d1 = 0, d2 = 0, d3 = 0;
    if (base + 3 < N_NODES) {
        int4 v = *(const int4*)(deg + base);
        d0 = v.x; d1 = v.y; d2 = v.z; d3 = v.w;
    } else if (base < N_NODES) {
        d0 = deg[base];
        if (base + 1 < N_NODES) d1 = deg[base + 1];
        if (base + 2 < N_NODES) d2 = deg[base + 2];
    }
    int s = d0 + d1 + d2 + d3;
    tsum[t] = s;
    __syncthreads();
    for (int off = 1; off < 256; off <<= 1) {
        int u = (t >= off) ? tsum[t - off] : 0;
        __syncthreads();
        tsum[t] += u;
        __syncthreads();
    }
    int run = bpre[blockIdx.x] + tsum[t] - s;
    if (base < N_NODES)     { row_ptr[base]     = run; cursor[base]     = run; run += d0; }
    if (base + 1 < N_NODES) { row_ptr[base + 1] = run; cursor[base + 1] = run; run += d1; }
    if (base + 2 < N_NODES) { row_ptr[base + 2] = run; cursor[base + 2] = run; run += d2; }
    if (base + 3 < N_NODES) { row_ptr[base + 3] = run; cursor[base + 3] = run; }
}

__global__ void fill_kernel(const int* __restrict__ ei, int* __restrict__ cursor,
                            int* __restrict__ col)
{
    int e = blockIdx.x * blockDim.x + threadIdx.x;
    if (e >= E_TOT) return;
    int s, d;
    if (e < E_ORIG) { s = ei[e]; d = ei[E_ORIG + e]; } else { s = d = e - E_ORIG; }
    int pos = atomicAdd(&cursor[d], 1);
    col[pos] = s;
}

// ---------------- slice-blocked gather, XCD-pinned, fused exp, 4 lanes x short8 ----------------
// slice = blockIdx.x % NBLK (-> XCD via round-robin), node-range = blockIdx.x / NBLK.
// w = exp(leaky(al_s[s]+al_d[n])) inline: the 4 lanes of an edge load the SAME al_s address
// (1 L2 request, broadcast), so redundancy costs ~6 VALU x 4 lanes per edge - cheaper than
// the 27 MB w-buffer round trip it replaces (R10 post-mortem).
template<int HC, int H, bool BN, bool OUTBF>
__global__ __launch_bounds__(256) void gat_gather_blk(const int* __restrict__ row_ptr,
                                                      const int* __restrict__ col,
                                                      const short* __restrict__ ht,
                                                      const float* __restrict__ al_s,
                                                      const float* __restrict__ al_d,
                                                      const float* __restrict__ bias,
                                                      const float* __restrict__ gamma,
                                                      const float* __restrict__ beta,
                                                      const float* __restrict__ mean,
                                                      const float* __restrict__ var,
                                                      void* __restrict__ outp)
{
    constexpr int NBLK = HC / 32;
    int blk  = blockIdx.x % NBLK;        // slice id == XCD id (mod 8)
    int nb   = blockIdx.x / NBLK;
    int n = nb * 64 + (threadIdx.x >> 2);
    if (n >= N_NODES) return;
    int lane  = threadIdx.x & 3;
    int head  = (blk * H) / NBLK;
    int c_loc = lane * 8;
    const short* hb  = ht + (size_t)blk * N_NODES * 32 + c_loc;
    const float* als = al_s + (size_t)head * N_NODES;
    float aldn = al_d[(size_t)head * N_NODES + n];
    int beg = row_ptr[n], end = row_ptr[n + 1];
    float a0 = 0.f, a1 = 0.f, a2 = 0.f, a3 = 0.f;
    float a4 = 0.f, a5 = 0.f, a6 = 0.f, a7 = 0.f, den = 0.f;
#define MKW(si, wi) { float v = als[si] + aldn; v = v > 0.f ? v : 0.2f * v; wi = __expf(v); }
#define ACC(hv, w) { \
        a0 = fmaf(w, bf2f(hv[0]), a0); a1 = fmaf(w, bf2f(hv[1]), a1); \
        a2 = fmaf(w, bf2f(hv[2]), a2); a3 = fmaf(w, bf2f(hv[3]), a3); \
        a4 = fmaf(w, bf2f(hv[4]), a4); a5 = fmaf(w, bf2f(hv[5]), a5); \
        a6 = fmaf(w, bf2f(hv[6]), a6); a7 = fmaf(w, bf2f(hv[7]), a7); }
    int e = beg;
    for (; e + 3 < end; e += 4) {
        int s0 = col[e], s1 = col[e + 1], s2 = col[e + 2], s3 = col[e + 3];
        float w0, w1, w2, w3;
        MKW(s0, w0); MKW(s1, w1); MKW(s2, w2); MKW(s3, w3);
        short8 h0 = *(const short8*)(hb + (size_t)s0 * 32);
        short8 h1 = *(const short8*)(hb + (size_t)s1 * 32);
        short8 h2 = *(const short8*)(hb + (size_t)s2 * 32);
        short8 h3 = *(const short8*)(hb + (size_t)s3 * 32);
        den += (w0 + w1) + (w2 + w3);
        ACC(h0, w0); ACC(h1, w1); ACC(h2, w2); ACC(h3, w3);
    }
    for (; e < end; ++e) {
        int s0 = col[e];
        float w0; MKW(s0, w0);
        short8 h0 = *(const short8*)(hb + (size_t)s0 * 32);
        den += w0;
        ACC(h0, w0);
    }
#undef ACC
#undef MKW
    float inv = 1.f / den;
    float r[8] = { a0 * inv, a1 * inv, a2 * inv, a3 * inv,
                   a4 * inv, a5 * inv, a6 * inv, a7 * inv };
    int cb = blk * 32 + c_loc;
#pragma unroll
    for (int j = 0; j < 8; ++j) {
        int c = cb + j;
        float v = r[j] + bias[c];
        if (BN) {
            v = (v - mean[c]) * rsqrtf(var[c] + 1e-5f) * gamma[c] + beta[c];
            v = v > 0.f ? v : expm1f(v);   // ELU
        }
        r[j] = v;
    }
    if (OUTBF) {
        short8 o;
#pragma unroll
        for (int j = 0; j < 8; ++j) o[j] = f2bf(r[j]);
        *(short8*)((short*)outp + (size_t)n * HC + cb) = o;
    } else {
        float* op = (float*)outp + (size_t)n * HC + cb;
        *(float4*)op       = make_float4(r[0], r[1], r[2], r[3]);
        *(float4*)(op + 4) = make_float4(r[4], r[5], r[6], r[7]);
    }
}

extern "C" void kernel_launch(void* const* d_in, const int* in_sizes, int n_in,
                              void* d_out, int out_size, void* d_ws, size_t ws_size,
                              hipStream_t stream)
{
    const float* x   = (const float*)d_in[0];
    const int*   ei  = (const int*)d_in[1];
    const float* W1  = (const float*)d_in[2];
    const float* as1 = (const float*)d_in[3];
    const float* ad1 = (const float*)d_in[4];
    const float* b1  = (const float*)d_in[5];
    const float* g1  = (const float*)d_in[6];
    const float* be1 = (const float*)d_in[7];
    const float* mn1 = (const float*)d_in[8];
    const float* vr1 = (const float*)d_in[9];
    const float* W2  = (const float*)d_in[10];
    const float* as2 = (const float*)d_in[11];
    const float* ad2 = (const float*)d_in[12];
    const float* b2  = (const float*)d_in[13];
    const float* g2  = (const float*)d_in[14];
    const float* be2 = (const float*)d_in[15];
    const float* mn2 = (const float*)d_in[16];
    const float* vr2 = (const float*)d_in[17];
    const float* W3  = (const float*)d_in[18];
    const float* as3 = (const float*)d_in[19];
    const float* ad3 = (const float*)d_in[20];
    const float* b3  = (const float*)d_in[21];

    char* p = (char*)d_ws;
    short* hbuf    = (short*)p; p += (size_t)N_NODES * 256 * 2;     // 25.6 MB (slice-major h)
    short* obuf    = (short*)p; p += (size_t)N_NODES * 256 * 2;     // 25.6 MB (row-major layer out)
    short* xbf     = (short*)p; p += (size_t)N_NODES * 128 * 2;     // 12.8 MB (bf16 x)
    short* wtbuf   = (short*)p; p += (size_t)131072 * 2;            // 256 KB (wt1|wt2|wt3)
    float* als     = (float*)p; p += (size_t)N_NODES * 8 * 4;       // head-major [h][n]
    float* ald     = (float*)p; p += (size_t)N_NODES * 8 * 4;
    int*   row_ptr = (int*)p;   p += (size_t)(N_NODES + 1) * 4;
    int*   col     = (int*)p;   p += (size_t)E_TOT * 4;
    int*   deg     = (int*)p;   p += (size_t)N_NODES * 4;
    int*   cursor  = (int*)p;   p += (size_t)N_NODES * 4;
    int*   bsum    = (int*)p;   p += 64 * 4;
    int*   bpre    = (int*)p;   p += 64 * 4;

    short* wt1 = wtbuf;           // [256][128]
    short* wt2 = wtbuf + 32768;   // [256][256]
    short* wt3 = wtbuf + 98304;   // [128][256]

    float* out = (float*)d_out;

    // ----- CSR build + upfront casts -----
    hipMemsetAsync(deg, 0, (size_t)N_NODES * 4, stream);
    deg_kernel<<<(E_TOT + 255) / 256, 256, 0, stream>>>(ei, deg);
    scan_p1<<<SNB, 256, 0, stream>>>(deg, bsum);
    scan_p2<<<1, 64, 0, stream>>>(bsum, bpre, row_ptr);
    scan_p3<<<SNB, 256, 0, stream>>>(deg, bpre, row_ptr, cursor);
    fill_kernel<<<(E_TOT + 255) / 256, 256, 0, stream>>>(ei, cursor, col);
    xcast_kernel<<<(N_NODES * 128 / 4 + 255) / 256, 256, 0, stream>>>(x, xbf, N_NODES * 128 / 4);
    wtcast_all<<<(131072 + 255) / 256, 256, 0, stream>>>(W1, W2, W3, wtbuf);

    const int nh8 = N_NODES * 8;

    // ----- layer 1: GAT(128 -> 8x32) + BN + ELU -----
    gemm_bf16<<<dim3(2, (N_NODES + 127) / 128), 256, 0, stream>>>(xbf, wt1, hbuf, N_NODES, 256, 128);
    logits_blk<8, 1><<<(nh8 + 255) / 256, 256, 0, stream>>>(hbuf, as1, ad1, als, ald);
    gat_gather_blk<256, 8, true, true><<<BPG * 8, 256, 0, stream>>>(
        row_ptr, col, hbuf, als, ald, b1, g1, be1, mn1, vr1, obuf);

    // ----- layer 2: GAT(256 -> 8x32) + BN + ELU -----
    gemm_bf16<<<dim3(2, (N_NODES + 127) / 128), 256, 0, stream>>>(obuf, wt2, hbuf, N_NODES, 256, 256);
    logits_blk<8, 1><<<(nh8 + 255) / 256, 256, 0, stream>>>(hbuf, as2, ad2, als, ald);
    gat_gather_blk<256, 8, true, true><<<BPG * 8, 256, 0, stream>>>(
        row_ptr, col, hbuf, als, ald, b2, g2, be2, mn2, vr2, obuf);

    // ----- layer 3: GAT(256 -> 1x128), heads=1 (mean == identity) -----
    gemm_bf16<<<dim3(1, (N_NODES + 127) / 128), 256, 0, stream>>>(obuf, wt3, hbuf, N_NODES, 128, 256);
    logits_blk<1, 4><<<(N_NODES + 255) / 256, 256, 0, stream>>>(hbuf, as3, ad3, als, ald);
    gat_gather_blk<128, 1, false, false><<<BPG * 4, 256, 0, stream>>>(
        row_ptr, col, hbuf, als, ald, b3, nullptr, nullptr, nullptr, nullptr, out);
}

// Round 12
// 527.349 us; speedup vs baseline: 1.1066x; 1.0392x over previous
//
#include <hip/hip_runtime.h>
#include <math.h>

#define N_NODES 50000
#define E_ORIG  800000
#define E_TOT   850000   // + self loops
#define SNB     49       // scan blocks: 49 * 1024 >= N_NODES
#define BPG     782      // gather node-blocks per slice: 782 * 64 >= N_NODES
#define CAP     1280     // LDS edge-window: mean block edge-count 1088, +5.8 sigma

typedef __attribute__((ext_vector_type(8))) short short8;   // 8 bf16 (4 VGPRs)
typedef __attribute__((ext_vector_type(4))) float f32x4;    // MFMA acc

__device__ __forceinline__ short f2bf(float f) {            // fp32 -> bf16 RNE
    unsigned u = __builtin_bit_cast(unsigned, f);
    u += 0x7FFFu + ((u >> 16) & 1u);
    return (short)(u >> 16);
}
__device__ __forceinline__ float bf2f(short s) {
    unsigned u = ((unsigned)(unsigned short)s) << 16;
    return __builtin_bit_cast(float, u);
}

// ---------------- bf16 MFMA GEMM: C_t[blk][m][32] = (A[M,K] @ W[K,N]) sliced ----------------
// 128x128 tile, BK=32, 4 waves = 64x64 quadrants. AF32: A is fp32, cast to bf16 in staging
// (fuses the old xcast pass into GEMM1).
template<bool AF32>
__global__ __launch_bounds__(256) void gemm_bf16(const void* __restrict__ Av,
                                                 const short* __restrict__ Wt,   // W^T [N][K]
                                                 short* __restrict__ C,          // [N/32][N_NODES][32]
                                                 int M, int N, int K)
{
    __shared__ short sA[128][40];
    __shared__ short sB[128][40];
    const int t    = threadIdx.x;
    const int wave = t >> 6, lane = t & 63;
    const int quad = lane >> 4, mrow = lane & 15;
    const int m0 = blockIdx.y * 128, n0 = blockIdx.x * 128;
    const int wm = (wave & 1) * 64, wn = (wave >> 1) * 64;

    f32x4 acc[4][4] = {};

    const int ra = t >> 2, ka = (t & 3) << 3;   // A: 2 passes of 64 rows, 8 elems each
    const int nb = t >> 1, kb = (t & 1) << 4;   // B: 128 rows, 16 shorts per thread

    for (int k0 = 0; k0 < K; k0 += 32) {
#pragma unroll
        for (int rr = 0; rr < 2; ++rr) {
            int row = ra + rr * 64;
            int gm = m0 + row;
            if (AF32) {
                const float* Af = (const float*)Av;
                float4 v0 = make_float4(0.f, 0.f, 0.f, 0.f), v1 = v0;
                if (gm < M) {
                    const float* src = Af + (size_t)gm * K + k0 + ka;
                    v0 = *(const float4*)src;
                    v1 = *(const float4*)(src + 4);
                }
                sA[row][ka + 0] = f2bf(v0.x); sA[row][ka + 1] = f2bf(v0.y);
                sA[row][ka + 2] = f2bf(v0.z); sA[row][ka + 3] = f2bf(v0.w);
                sA[row][ka + 4] = f2bf(v1.x); sA[row][ka + 5] = f2bf(v1.y);
                sA[row][ka + 6] = f2bf(v1.z); sA[row][ka + 7] = f2bf(v1.w);
            } else {
                const short* Ab = (const short*)Av;
                int4 v = {0, 0, 0, 0};
                if (gm < M) v = *(const int4*)(Ab + (size_t)gm * K + k0 + ka);
                *(int4*)&sA[row][ka] = v;
            }
        }
        {
            const int4* src = (const int4*)(Wt + (size_t)(n0 + nb) * K + k0 + kb);
            *(int4*)&sB[nb][kb]     = src[0];
            *(int4*)&sB[nb][kb + 8] = src[1];
        }
        __syncthreads();
        short8 af[4], bfr[4];
#pragma unroll
        for (int mi = 0; mi < 4; ++mi)
            af[mi] = *(const short8*)&sA[wm + mi * 16 + mrow][quad * 8];
#pragma unroll
        for (int ni = 0; ni < 4; ++ni)
            bfr[ni] = *(const short8*)&sB[wn + ni * 16 + mrow][quad * 8];
#pragma unroll
        for (int mi = 0; mi < 4; ++mi)
#pragma unroll
            for (int ni = 0; ni < 4; ++ni)
                acc[mi][ni] = __builtin_amdgcn_mfma_f32_16x16x32_bf16(af[mi], bfr[ni], acc[mi][ni], 0, 0, 0);
        __syncthreads();
    }
    // C/D layout: col = lane&15, row = quad*4 + reg; write slice-major
#pragma unroll
    for (int mi = 0; mi < 4; ++mi) {
#pragma unroll
        for (int ni = 0; ni < 4; ++ni) {
            int gn = n0 + wn + ni * 16 + mrow;
            size_t sbase = ((size_t)(gn >> 5) * N_NODES) * 32 + (gn & 31);
            int gmb = m0 + wm + mi * 16 + quad * 4;
#pragma unroll
            for (int r = 0; r < 4; ++r) {
                int gm = gmb + r;
                if (gm < M) C[sbase + (size_t)gm * 32] = f2bf(acc[mi][ni][r]);
            }
        }
    }
}

// ---------------- W^T casts, one launch ----------------
__global__ void wtcast_all(const float* __restrict__ W1, const float* __restrict__ W2,
                           const float* __restrict__ W3, short* __restrict__ wt)
{
    int i = blockIdx.x * blockDim.x + threadIdx.x;
    if (i < 32768) {                       // W1: K=128, N=256
        int n = i / 128, k = i % 128;
        wt[i] = f2bf(W1[(size_t)k * 256 + n]);
    } else if (i < 98304) {                // W2: K=256, N=256
        int j = i - 32768;
        int n = j / 256, k = j % 256;
        wt[i] = f2bf(W2[(size_t)k * 256 + n]);
    } else if (i < 131072) {               // W3: K=256, N=128
        int j = i - 98304;
        int n = j / 256, k = j % 256;
        wt[i] = f2bf(W3[(size_t)k * 128 + n]);
    }
}

// ---------------- attention logits, head-major outputs: al[h][n] ----------------
template<int H, int BPH>
__global__ void logits_blk(const short* __restrict__ ht,
                           const float* __restrict__ a_src,
                           const float* __restrict__ a_dst,
                           float* __restrict__ al_s, float* __restrict__ al_d)
{
    int i = blockIdx.x * blockDim.x + threadIdx.x;
    if (i >= N_NODES * H) return;
    int n = i / H, hh = i % H;
    float ss = 0.f, sd = 0.f;
#pragma unroll
    for (int b = 0; b < BPH; ++b) {
        int blk = hh * BPH + b;
        const short* hp = ht + ((size_t)blk * N_NODES + n) * 32;
        const float* as = a_src + blk * 32;
        const float* ad = a_dst + blk * 32;
#pragma unroll
        for (int c8 = 0; c8 < 32; c8 += 8) {
            short8 hv = *(const short8*)(hp + c8);
#pragma unroll
            for (int j = 0; j < 8; ++j) {
                float v = bf2f(hv[j]);
                ss = fmaf(v, as[c8 + j], ss);
                sd = fmaf(v, ad[c8 + j], sd);
            }
        }
    }
    al_s[(size_t)hh * N_NODES + n] = ss;
    al_d[(size_t)hh * N_NODES + n] = sd;
}

// ---------------- CSR build ----------------
__global__ void deg_kernel(const int* __restrict__ ei, int* __restrict__ deg)
{
    int e = blockIdx.x * blockDim.x + threadIdx.x;
    if (e >= E_TOT) return;
    int d = (e < E_ORIG) ? ei[E_ORIG + e] : e - E_ORIG;
    atomicAdd(&deg[d], 1);
}

__global__ __launch_bounds__(256) void scan_p1(const int* __restrict__ deg, int* __restrict__ bsum)
{
    __shared__ int wsum[4];
    int t = threadIdx.x;
    int base = blockIdx.x * 1024 + t * 4;
    int s = 0;
    if (base + 3 < N_NODES) {
        int4 v = *(const int4*)(deg + base);
        s = v.x + v.y + v.z + v.w;
    } else if (base < N_NODES) {
        for (int j = 0; j < 4 && base + j < N_NODES; ++j) s += deg[base + j];
    }
#pragma unroll
    for (int d = 32; d; d >>= 1) s += __shfl_down(s, d);
    if ((t & 63) == 0) wsum[t >> 6] = s;
    __syncthreads();
    if (t == 0) bsum[blockIdx.x] = wsum[0] + wsum[1] + wsum[2] + wsum[3];
}

__global__ void scan_p2(const int* __restrict__ bsum, int* __restrict__ bpre,
                        int* __restrict__ row_ptr)
{
    int t = threadIdx.x;   // 64 threads
    int v = (t < SNB) ? bsum[t] : 0;
    int inc = v;
#pragma unroll
    for (int d = 1; d < 64; d <<= 1) {
        int u = __shfl_up(inc, d);
        if (t >= d) inc += u;
    }
    if (t < SNB) bpre[t] = inc - v;
    if (t == SNB - 1) row_ptr[N_NODES] = inc;
}

__global__ __launch_bounds__(256) void scan_p3(const int* __restrict__ deg,
                                               const int* __restrict__ bpre,
                                               int* __restrict__ row_ptr,
                                               int* __restrict__ cursor)
{
    __shared__ int tsum[256];
    int t = threadIdx.x;
    int base = blockIdx.x * 1024 + t * 4;
    int d0 = 0, d1 = 0, d2 = 0, d3 = 0;
    if (base + 3 < N_NODES) {
        int4 v = *(const int4*)(deg + base);
        d0 = v.x; d1 = v.y; d2 = v.z; d3 = v.w;
    } else if (base < N_NODES) {
        d0 = deg[base];
        if (base + 1 < N_NODES) d1 = deg[base + 1];
        if (base + 2 < N_NODES) d2 = deg[base + 2];
    }
    int s = d0 + d1 + d2 + d3;
    tsum[t] = s;
    __syncthreads();
    for (int off = 1; off < 256; off <<= 1) {
        int u = (t >= off) ? tsum[t - off] : 0;
        __syncthreads();
        tsum[t] += u;
        __syncthreads();
    }
    int run = bpre[blockIdx.x] + tsum[t] - s;
    if (base < N_NODES)     { row_ptr[base]     = run; cursor[base]     = run; run += d0; }
    if (base + 1 < N_NODES) { row_ptr[base + 1] = run; cursor[base + 1] = run; run += d1; }
    if (base + 2 < N_NODES) { row_ptr[base + 2] = run; cursor[base + 2] = run; run += d2; }
    if (base + 3 < N_NODES) { row_ptr[base + 3] = run; cursor[base + 3] = run; }
}

__global__ void fill_kernel(const int* __restrict__ ei, int* __restrict__ cursor,
                            int* __restrict__ col, int* __restrict__ dstv)
{
    int e = blockIdx.x * blockDim.x + threadIdx.x;
    if (e >= E_TOT) return;
    int s, d;
    if (e < E_ORIG) { s = ei[e]; d = ei[E_ORIG + e]; } else { s = d = e - E_ORIG; }
    int pos = atomicAdd(&cursor[d], 1);
    col[pos] = s;
    dstv[pos] = d;
}

// ---------------- slice-blocked gather, XCD-pinned, LDS-staged edges ----------------
// A block's 64 nodes own a contiguous CSR range (~1088 edges). Cooperative staging:
// each edge handled by ONE thread (coalesced col/dstv; al_d hits only the block's 64
// nodes; exp computed once per edge, not x4 lanes). Main loop: ds_read_b64 {col,w}
// (broadcast across an edge's 4 lanes) + 16B h-load + cvt/fma. Summation order per
// node unchanged -> bit-identical to R11.
template<int HC, int H, bool BN, bool OUTBF>
__global__ __launch_bounds__(256) void gat_gather_lds(const int* __restrict__ row_ptr,
                                                      const int* __restrict__ col,
                                                      const int* __restrict__ dstv,
                                                      const short* __restrict__ ht,
                                                      const float* __restrict__ al_s,
                                                      const float* __restrict__ al_d,
                                                      const float* __restrict__ bias,
                                                      const float* __restrict__ gamma,
                                                      const float* __restrict__ beta,
                                                      const float* __restrict__ mean,
                                                      const float* __restrict__ var,
                                                      void* __restrict__ outp)
{
    constexpr int NBLK = HC / 32;
    __shared__ int2 s_cw[CAP];           // {src node, bitcast(w)}
    int blk  = blockIdx.x % NBLK;        // slice id == XCD id (mod 8)
    int nb   = blockIdx.x / NBLK;
    int t    = threadIdx.x;
    int n    = nb * 64 + (t >> 2);
    int lane = t & 3;
    int head = (blk * H) / NBLK;
    int c_loc = lane * 8;
    const short* hb  = ht + (size_t)blk * N_NODES * 32 + c_loc;
    const float* als = al_s + (size_t)head * N_NODES;
    const float* ald = al_d + (size_t)head * N_NODES;

    int n0 = nb * 64;
    int n1 = n0 + 64; if (n1 > N_NODES) n1 = N_NODES;
    int eb = row_ptr[n0], ee = row_ptr[n1];   // block-uniform window bounds

    int mybeg = 0, myend = 0;
    if (n < N_NODES) { mybeg = row_ptr[n]; myend = row_ptr[n + 1]; }

    float a0 = 0.f, a1 = 0.f, a2 = 0.f, a3 = 0.f;
    float a4 = 0.f, a5 = 0.f, a6 = 0.f, a7 = 0.f, den = 0.f;
#define ACC(hv, w) { \
        a0 = fmaf(w, bf2f(hv[0]), a0); a1 = fmaf(w, bf2f(hv[1]), a1); \
        a2 = fmaf(w, bf2f(hv[2]), a2); a3 = fmaf(w, bf2f(hv[3]), a3); \
        a4 = fmaf(w, bf2f(hv[4]), a4); a5 = fmaf(w, bf2f(hv[5]), a5); \
        a6 = fmaf(w, bf2f(hv[6]), a6); a7 = fmaf(w, bf2f(hv[7]), a7); }

    for (int w0 = eb; w0 < ee; w0 += CAP) {
        int w1 = w0 + CAP; if (w1 > ee) w1 = ee;
        // ---- cooperative staging (coalesced; one thread per edge) ----
        for (int i = w0 + t; i < w1; i += 256) {
            int c = col[i], d = dstv[i];
            float v = als[c] + ald[d];
            v = v > 0.f ? v : 0.2f * v;
            s_cw[i - w0] = make_int2(c, __float_as_int(__expf(v)));
        }
        __syncthreads();
        // ---- per-node accumulate from LDS ----
        int lo = mybeg > w0 ? mybeg : w0;
        int hi = myend < w1 ? myend : w1;
        int e = lo;
        for (; e + 3 < hi; e += 4) {
            int2 cw0 = s_cw[e - w0],     cw1 = s_cw[e - w0 + 1];
            int2 cw2 = s_cw[e - w0 + 2], cw3 = s_cw[e - w0 + 3];
            short8 h0 = *(const short8*)(hb + (size_t)cw0.x * 32);
            short8 h1 = *(const short8*)(hb + (size_t)cw1.x * 32);
            short8 h2 = *(const short8*)(hb + (size_t)cw2.x * 32);
            short8 h3 = *(const short8*)(hb + (size_t)cw3.x * 32);
            float w0v = __int_as_float(cw0.y), w1v = __int_as_float(cw1.y);
            float w2v = __int_as_float(cw2.y), w3v = __int_as_float(cw3.y);
            den += (w0v + w1v) + (w2v + w3v);
            ACC(h0, w0v); ACC(h1, w1v); ACC(h2, w2v); ACC(h3, w3v);
        }
        for (; e < hi; ++e) {
            int2 cw = s_cw[e - w0];
            short8 h0 = *(const short8*)(hb + (size_t)cw.x * 32);
            float wv = __int_as_float(cw.y);
            den += wv;
            ACC(h0, wv);
        }
        __syncthreads();
    }
#undef ACC
    if (n >= N_NODES) return;
    float inv = 1.f / den;
    float r[8] = { a0 * inv, a1 * inv, a2 * inv, a3 * inv,
                   a4 * inv, a5 * inv, a6 * inv, a7 * inv };
    int cb = blk * 32 + c_loc;
#pragma unroll
    for (int j = 0; j < 8; ++j) {
        int c = cb + j;
        float v = r[j] + bias[c];
        if (BN) {
            v = (v - mean[c]) * rsqrtf(var[c] + 1e-5f) * gamma[c] + beta[c];
            v = v > 0.f ? v : expm1f(v);   // ELU
        }
        r[j] = v;
    }
    if (OUTBF) {
        short8 o;
#pragma unroll
        for (int j = 0; j < 8; ++j) o[j] = f2bf(r[j]);
        *(short8*)((short*)outp + (size_t)n * HC + cb) = o;
    } else {
        float* op = (float*)outp + (size_t)n * HC + cb;
        *(float4*)op       = make_float4(r[0], r[1], r[2], r[3]);
        *(float4*)(op + 4) = make_float4(r[4], r[5], r[6], r[7]);
    }
}

extern "C" void kernel_launch(void* const* d_in, const int* in_sizes, int n_in,
                              void* d_out, int out_size, void* d_ws, size_t ws_size,
                              hipStream_t stream)
{
    const float* x   = (const float*)d_in[0];
    const int*   ei  = (const int*)d_in[1];
    const float* W1  = (const float*)d_in[2];
    const float* as1 = (const float*)d_in[3];
    const float* ad1 = (const float*)d_in[4];
    const float* b1  = (const float*)d_in[5];
    const float* g1  = (const float*)d_in[6];
    const float* be1 = (const float*)d_in[7];
    const float* mn1 = (const float*)d_in[8];
    const float* vr1 = (const float*)d_in[9];
    const float* W2  = (const float*)d_in[10];
    const float* as2 = (const float*)d_in[11];
    const float* ad2 = (const float*)d_in[12];
    const float* b2  = (const float*)d_in[13];
    const float* g2  = (const float*)d_in[14];
    const float* be2 = (const float*)d_in[15];
    const float* mn2 = (const float*)d_in[16];
    const float* vr2 = (const float*)d_in[17];
    const float* W3  = (const float*)d_in[18];
    const float* as3 = (const float*)d_in[19];
    const float* ad3 = (const float*)d_in[20];
    const float* b3  = (const float*)d_in[21];

    char* p = (char*)d_ws;
    short* hbuf    = (short*)p; p += (size_t)N_NODES * 256 * 2;     // 25.6 MB (slice-major h)
    short* obuf    = (short*)p; p += (size_t)N_NODES * 256 * 2;     // 25.6 MB (row-major layer out)
    short* wtbuf   = (short*)p; p += (size_t)131072 * 2;            // 256 KB (wt1|wt2|wt3)
    float* als     = (float*)p; p += (size_t)N_NODES * 8 * 4;       // head-major [h][n]
    float* ald     = (float*)p; p += (size_t)N_NODES * 8 * 4;
    int*   row_ptr = (int*)p;   p += (size_t)(N_NODES + 1) * 4;
    int*   col     = (int*)p;   p += (size_t)E_TOT * 4;
    int*   dstv    = (int*)p;   p += (size_t)E_TOT * 4;
    int*   deg     = (int*)p;   p += (size_t)N_NODES * 4;
    int*   cursor  = (int*)p;   p += (size_t)N_NODES * 4;
    int*   bsum    = (int*)p;   p += 64 * 4;
    int*   bpre    = (int*)p;   p += 64 * 4;

    short* wt1 = wtbuf;           // [256][128]
    short* wt2 = wtbuf + 32768;   // [256][256]
    short* wt3 = wtbuf + 98304;   // [128][256]

    float* out = (float*)d_out;

    // ----- CSR build + weight casts -----
    hipMemsetAsync(deg, 0, (size_t)N_NODES * 4, stream);
    deg_kernel<<<(E_TOT + 255) / 256, 256, 0, stream>>>(ei, deg);
    scan_p1<<<SNB, 256, 0, stream>>>(deg, bsum);
    scan_p2<<<1, 64, 0, stream>>>(bsum, bpre, row_ptr);
    scan_p3<<<SNB, 256, 0, stream>>>(deg, bpre, row_ptr, cursor);
    fill_kernel<<<(E_TOT + 255) / 256, 256, 0, stream>>>(ei, cursor, col, dstv);
    wtcast_all<<<(131072 + 255) / 256, 256, 0, stream>>>(W1, W2, W3, wtbuf);

    const int nh8 = N_NODES * 8;

    // ----- layer 1: GAT(128 -> 8x32) + BN + ELU (fp32 x cast in GEMM staging) -----
    gemm_bf16<true><<<dim3(2, (N_NODES + 127) / 128), 256, 0, stream>>>(x, wt1, hbuf, N_NODES, 256, 128);
    logits_blk<8, 1><<<(nh8 + 255) / 256, 256, 0, stream>>>(hbuf, as1, ad1, als, ald);
    gat_gather_lds<256, 8, true, true><<<BPG * 8, 256, 0, stream>>>(
        row_ptr, col, dstv, hbuf, als, ald, b1, g1, be1, mn1, vr1, obuf);

    // ----- layer 2: GAT(256 -> 8x32) + BN + ELU -----
    gemm_bf16<false><<<dim3(2, (N_NODES + 127) / 128), 256, 0, stream>>>(obuf, wt2, hbuf, N_NODES, 256, 256);
    logits_blk<8, 1><<<(nh8 + 255) / 256, 256, 0, stream>>>(hbuf, as2, ad2, als, ald);
    gat_gather_lds<256, 8, true, true><<<BPG * 8, 256, 0, stream>>>(
        row_ptr, col, dstv, hbuf, als, ald, b2, g2, be2, mn2, vr2, obuf);

    // ----- layer 3: GAT(256 -> 1x128), heads=1 (mean == identity) -----
    gemm_bf16<false><<<dim3(1, (N_NODES + 127) / 128), 256, 0, stream>>>(obuf, wt3, hbuf, N_NODES, 128, 256);
    logits_blk<1, 4><<<(N_NODES + 255) / 256, 256, 0, stream>>>(hbuf, as3, ad3, als, ald);
    gat_gather_lds<128, 1, false, false><<<BPG * 4, 256, 0, stream>>>(
        row_ptr, col, dstv, hbuf, als, ald, b3, nullptr, nullptr, nullptr, nullptr, out);
}

// Round 13
// 526.667 us; speedup vs baseline: 1.1080x; 1.0013x over previous
//
#include <hip/hip_runtime.h>
#include <hip/hip_fp16.h>
#include <math.h>

#define N_NODES 50000
#define E_ORIG  800000
#define E_TOT   850000   // + self loops
#define SNB     49       // scan blocks: 49 * 1024 >= N_NODES
#define BPG     782      // gather node-blocks per slice: 782 * 64 >= N_NODES
#define CAP     1280     // LDS edge-window: mean block edge-count 1088, +5.8 sigma
#define WSCALE  0.00390625f   // 2^-8: keeps half2(w) < fp16 max up to logit ~16.6
#define WUNSCALE 256.0f

typedef __attribute__((ext_vector_type(8))) short    short8;
typedef __attribute__((ext_vector_type(8))) _Float16 half8;
typedef __attribute__((ext_vector_type(4))) float    f32x4;

__device__ __forceinline__ short f2h(float f) {             // fp32 -> fp16 RNE
    _Float16 h = (_Float16)f;
    return __builtin_bit_cast(short, h);
}
__device__ __forceinline__ float h2f(short s) {
    _Float16 h = __builtin_bit_cast(_Float16, s);
    return (float)h;
}

// ---------------- fp16 MFMA GEMM: C_t[blk][m][32] = (A[M,K] @ W[K,N]) sliced ----------------
// 128x128 tile, BK=32, 4 waves = 64x64 quadrants. AF32: A fp32, cast to fp16 in staging.
template<bool AF32>
__global__ __launch_bounds__(256) void gemm_f16(const void* __restrict__ Av,
                                                const short* __restrict__ Wt,   // W^T [N][K] fp16
                                                short* __restrict__ C,          // [N/32][N_NODES][32]
                                                int M, int N, int K)
{
    __shared__ short sA[128][40];
    __shared__ short sB[128][40];
    const int t    = threadIdx.x;
    const int wave = t >> 6, lane = t & 63;
    const int quad = lane >> 4, mrow = lane & 15;
    const int m0 = blockIdx.y * 128, n0 = blockIdx.x * 128;
    const int wm = (wave & 1) * 64, wn = (wave >> 1) * 64;

    f32x4 acc[4][4] = {};

    const int ra = t >> 2, ka = (t & 3) << 3;   // A: 2 passes of 64 rows, 8 elems each
    const int nb = t >> 1, kb = (t & 1) << 4;   // B: 128 rows, 16 shorts per thread

    for (int k0 = 0; k0 < K; k0 += 32) {
#pragma unroll
        for (int rr = 0; rr < 2; ++rr) {
            int row = ra + rr * 64;
            int gm = m0 + row;
            if (AF32) {
                const float* Af = (const float*)Av;
                float4 v0 = make_float4(0.f, 0.f, 0.f, 0.f), v1 = v0;
                if (gm < M) {
                    const float* src = Af + (size_t)gm * K + k0 + ka;
                    v0 = *(const float4*)src;
                    v1 = *(const float4*)(src + 4);
                }
                sA[row][ka + 0] = f2h(v0.x); sA[row][ka + 1] = f2h(v0.y);
                sA[row][ka + 2] = f2h(v0.z); sA[row][ka + 3] = f2h(v0.w);
                sA[row][ka + 4] = f2h(v1.x); sA[row][ka + 5] = f2h(v1.y);
                sA[row][ka + 6] = f2h(v1.z); sA[row][ka + 7] = f2h(v1.w);
            } else {
                const short* Ab = (const short*)Av;
                int4 v = {0, 0, 0, 0};
                if (gm < M) v = *(const int4*)(Ab + (size_t)gm * K + k0 + ka);
                *(int4*)&sA[row][ka] = v;
            }
        }
        {
            const int4* src = (const int4*)(Wt + (size_t)(n0 + nb) * K + k0 + kb);
            *(int4*)&sB[nb][kb]     = src[0];
            *(int4*)&sB[nb][kb + 8] = src[1];
        }
        __syncthreads();
        short8 af[4], bfr[4];
#pragma unroll
        for (int mi = 0; mi < 4; ++mi)
            af[mi] = *(const short8*)&sA[wm + mi * 16 + mrow][quad * 8];
#pragma unroll
        for (int ni = 0; ni < 4; ++ni)
            bfr[ni] = *(const short8*)&sB[wn + ni * 16 + mrow][quad * 8];
#pragma unroll
        for (int mi = 0; mi < 4; ++mi)
#pragma unroll
            for (int ni = 0; ni < 4; ++ni)
                acc[mi][ni] = __builtin_amdgcn_mfma_f32_16x16x32_f16(
                    __builtin_bit_cast(half8, af[mi]),
                    __builtin_bit_cast(half8, bfr[ni]), acc[mi][ni], 0, 0, 0);
        __syncthreads();
    }
    // C/D layout: col = lane&15, row = quad*4 + reg; write slice-major
#pragma unroll
    for (int mi = 0; mi < 4; ++mi) {
#pragma unroll
        for (int ni = 0; ni < 4; ++ni) {
            int gn = n0 + wn + ni * 16 + mrow;
            size_t sbase = ((size_t)(gn >> 5) * N_NODES) * 32 + (gn & 31);
            int gmb = m0 + wm + mi * 16 + quad * 4;
#pragma unroll
            for (int r = 0; r < 4; ++r) {
                int gm = gmb + r;
                if (gm < M) C[sbase + (size_t)gm * 32] = f2h(acc[mi][ni][r]);
            }
        }
    }
}

// ---------------- W^T casts, one launch ----------------
__global__ void wtcast_all(const float* __restrict__ W1, const float* __restrict__ W2,
                           const float* __restrict__ W3, short* __restrict__ wt)
{
    int i = blockIdx.x * blockDim.x + threadIdx.x;
    if (i < 32768) {                       // W1: K=128, N=256
        int n = i / 128, k = i % 128;
        wt[i] = f2h(W1[(size_t)k * 256 + n]);
    } else if (i < 98304) {                // W2: K=256, N=256
        int j = i - 32768;
        int n = j / 256, k = j % 256;
        wt[i] = f2h(W2[(size_t)k * 256 + n]);
    } else if (i < 131072) {               // W3: K=256, N=128
        int j = i - 98304;
        int n = j / 256, k = j % 256;
        wt[i] = f2h(W3[(size_t)k * 128 + n]);
    }
}

// ---------------- attention logits, head-major outputs: al[h][n] ----------------
template<int H, int BPH>
__global__ void logits_blk(const short* __restrict__ ht,
                           const float* __restrict__ a_src,
                           const float* __restrict__ a_dst,
                           float* __restrict__ al_s, float* __restrict__ al_d)
{
    int i = blockIdx.x * blockDim.x + threadIdx.x;
    if (i >= N_NODES * H) return;
    int n = i / H, hh = i % H;
    float ss = 0.f, sd = 0.f;
#pragma unroll
    for (int b = 0; b < BPH; ++b) {
        int blk = hh * BPH + b;
        const short* hp = ht + ((size_t)blk * N_NODES + n) * 32;
        const float* as = a_src + blk * 32;
        const float* ad = a_dst + blk * 32;
#pragma unroll
        for (int c8 = 0; c8 < 32; c8 += 8) {
            short8 hv = *(const short8*)(hp + c8);
#pragma unroll
            for (int j = 0; j < 8; ++j) {
                float v = h2f(hv[j]);
                ss = fmaf(v, as[c8 + j], ss);
                sd = fmaf(v, ad[c8 + j], sd);
            }
        }
    }
    al_s[(size_t)hh * N_NODES + n] = ss;
    al_d[(size_t)hh * N_NODES + n] = sd;
}

// ---------------- CSR build ----------------
__global__ void deg_kernel(const int* __restrict__ ei, int* __restrict__ deg)
{
    int e = blockIdx.x * blockDim.x + threadIdx.x;
    if (e >= E_TOT) return;
    int d = (e < E_ORIG) ? ei[E_ORIG + e] : e - E_ORIG;
    atomicAdd(&deg[d], 1);
}

__global__ __launch_bounds__(256) void scan_p1(const int* __restrict__ deg, int* __restrict__ bsum)
{
    __shared__ int wsum[4];
    int t = threadIdx.x;
    int base = blockIdx.x * 1024 + t * 4;
    int s = 0;
    if (base + 3 < N_NODES) {
        int4 v = *(const int4*)(deg + base);
        s = v.x + v.y + v.z + v.w;
    } else if (base < N_NODES) {
        for (int j = 0; j < 4 && base + j < N_NODES; ++j) s += deg[base + j];
    }
#pragma unroll
    for (int d = 32; d; d >>= 1) s += __shfl_down(s, d);
    if ((t & 63) == 0) wsum[t >> 6] = s;
    __syncthreads();
    if (t == 0) bsum[blockIdx.x] = wsum[0] + wsum[1] + wsum[2] + wsum[3];
}

__global__ void scan_p2(const int* __restrict__ bsum, int* __restrict__ bpre,
                        int* __restrict__ row_ptr)
{
    int t = threadIdx.x;   // 64 threads
    int v = (t < SNB) ? bsum[t] : 0;
    int inc = v;
#pragma unroll
    for (int d = 1; d < 64; d <<= 1) {
        int u = __shfl_up(inc, d);
        if (t >= d) inc += u;
    }
    if (t < SNB) bpre[t] = inc - v;
    if (t == SNB - 1) row_ptr[N_NODES] = inc;
}

__global__ __launch_bounds__(256) void scan_p3(const int* __restrict__ deg,
                                               const int* __restrict__ bpre,
                                               int* __restrict__ row_ptr,
                                               int* __restrict__ cursor)
{
    __shared__ int tsum[256];
    int t = threadIdx.x;
    int base = blockIdx.x * 1024 + t * 4;
    int d0 = 0, d1 = 0, d2 = 0, d3 = 0;
    if (base + 3 < N_NODES) {
        int4 v = *(const int4*)(deg + base);
        d0 = v.x; d1 = v.y; d2 = v.z; d3 = v.w;
    } else if (base < N_NODES) {
        d0 = deg[base];
        if (base + 1 < N_NODES) d1 = deg[base + 1];
        if (base + 2 < N_NODES) d2 = deg[base + 2];
    }
    int s = d0 + d1 + d2 + d3;
    tsum[t] = s;
    __syncthreads();
    for (int off = 1; off < 256; off <<= 1) {
        int u = (t >= off) ? tsum[t - off] : 0;
        __syncthreads();
        tsum[t] += u;
        __syncthreads();
    }
    int run = bpre[blockIdx.x] + tsum[t] - s;
    if (base < N_NODES)     { row_ptr[base]     = run; cursor[base]     = run; run += d0; }
    if (base + 1 < N_NODES) { row_ptr[base + 1] = run; cursor[base + 1] = run; run += d1; }
    if (base + 2 < N_NODES) { row_ptr[base + 2] = run; cursor[base + 2] = run; run += d2; }
    if (base + 3 < N_NODES) { row_ptr[base + 3] = run; cursor[base + 3] = run; }
}

__global__ void fill_kernel(const int* __restrict__ ei, int* __restrict__ cursor,
                            int* __restrict__ col, int* __restrict__ dstv)
{
    int e = blockIdx.x * blockDim.x + threadIdx.x;
    if (e >= E_TOT) return;
    int s, d;
    if (e < E_ORIG) { s = ei[e]; d = ei[E_ORIG + e]; } else { s = d = e - E_ORIG; }
    int pos = atomicAdd(&cursor[d], 1);
    col[pos] = s;
    dstv[pos] = d;
}

// ---------------- slice-blocked gather, XCD-pinned, LDS-staged edges, half2 fma ----------------
// Staged entry: {col, f32 w (den), half2(w*2^-8) (acc), pad}. Inner loop per edge:
// 1 ds_read_b128 (broadcast across an edge's 4 lanes) + 16B h-load + 4 v_pk_fma_f16 + 1 add
// (vs 16 cvt+fma in the fp32 path). w scaled by 2^-8 so half2 never overflows (logit<16.6);
// exact power-of-2, un-done by inv = 256/den.
template<int HC, int H, bool BN, bool OUTH>
__global__ __launch_bounds__(256) void gat_gather_lds(const int* __restrict__ row_ptr,
                                                      const int* __restrict__ col,
                                                      const int* __restrict__ dstv,
                                                      const short* __restrict__ ht,
                                                      const float* __restrict__ al_s,
                                                      const float* __restrict__ al_d,
                                                      const float* __restrict__ bias,
                                                      const float* __restrict__ gamma,
                                                      const float* __restrict__ beta,
                                                      const float* __restrict__ mean,
                                                      const float* __restrict__ var,
                                                      void* __restrict__ outp)
{
    constexpr int NBLK = HC / 32;
    __shared__ int4 s_cw[CAP];           // {src, f32 w, half2 w*2^-8, pad}
    int blk  = blockIdx.x % NBLK;        // slice id == XCD id (mod 8)
    int nb   = blockIdx.x / NBLK;
    int t    = threadIdx.x;
    int n    = nb * 64 + (t >> 2);
    int lane = t & 3;
    int head = (blk * H) / NBLK;
    int c_loc = lane * 8;
    const short* hb  = ht + (size_t)blk * N_NODES * 32 + c_loc;
    const float* als = al_s + (size_t)head * N_NODES;
    const float* ald = al_d + (size_t)head * N_NODES;

    int n0 = nb * 64;
    int n1 = n0 + 64; if (n1 > N_NODES) n1 = N_NODES;
    int eb = row_ptr[n0], ee = row_ptr[n1];   // block-uniform window bounds

    int mybeg = 0, myend = 0;
    if (n < N_NODES) { mybeg = row_ptr[n]; myend = row_ptr[n + 1]; }

    __half2 acc0 = __float2half2_rn(0.f), acc1 = acc0, acc2 = acc0, acc3 = acc0;
    float den = 0.f;
#define ACC(hv, w2) { \
        acc0 = __hfma2(w2, __builtin_bit_cast(__half2, hv.x), acc0); \
        acc1 = __hfma2(w2, __builtin_bit_cast(__half2, hv.y), acc1); \
        acc2 = __hfma2(w2, __builtin_bit_cast(__half2, hv.z), acc2); \
        acc3 = __hfma2(w2, __builtin_bit_cast(__half2, hv.w), acc3); }

    for (int w0 = eb; w0 < ee; w0 += CAP) {
        int w1 = w0 + CAP; if (w1 > ee) w1 = ee;
        // ---- cooperative staging (coalesced; one thread per edge) ----
        for (int i = w0 + t; i < w1; i += 256) {
            int c = col[i], d = dstv[i];
            float v = als[c] + ald[d];
            v = v > 0.f ? v : 0.2f * v;
            float w = __expf(v);
            __half2 w2 = __float2half2_rn(w * WSCALE);
            s_cw[i - w0] = make_int4(c, __float_as_int(w),
                                     __builtin_bit_cast(int, w2), 0);
        }
        __syncthreads();
        // ---- per-node accumulate from LDS ----
        int lo = mybeg > w0 ? mybeg : w0;
        int hi = myend < w1 ? myend : w1;
        int e = lo;
        for (; e + 3 < hi; e += 4) {
            int4 cw0 = s_cw[e - w0],     cw1 = s_cw[e - w0 + 1];
            int4 cw2 = s_cw[e - w0 + 2], cw3 = s_cw[e - w0 + 3];
            int4 h0 = *(const int4*)(hb + (size_t)cw0.x * 32);
            int4 h1 = *(const int4*)(hb + (size_t)cw1.x * 32);
            int4 h2 = *(const int4*)(hb + (size_t)cw2.x * 32);
            int4 h3 = *(const int4*)(hb + (size_t)cw3.x * 32);
            den += (__int_as_float(cw0.y) + __int_as_float(cw1.y))
                 + (__int_as_float(cw2.y) + __int_as_float(cw3.y));
            __half2 w20 = __builtin_bit_cast(__half2, cw0.z);
            __half2 w21 = __builtin_bit_cast(__half2, cw1.z);
            __half2 w22 = __builtin_bit_cast(__half2, cw2.z);
            __half2 w23 = __builtin_bit_cast(__half2, cw3.z);
            ACC(h0, w20); ACC(h1, w21); ACC(h2, w22); ACC(h3, w23);
        }
        for (; e < hi; ++e) {
            int4 cw = s_cw[e - w0];
            int4 h0 = *(const int4*)(hb + (size_t)cw.x * 32);
            den += __int_as_float(cw.y);
            __half2 w2 = __builtin_bit_cast(__half2, cw.z);
            ACC(h0, w2);
        }
        __syncthreads();
    }
#undef ACC
    if (n >= N_NODES) return;
    float inv = WUNSCALE / den;
    float2 f0 = __half22float2(acc0), f1 = __half22float2(acc1);
    float2 f2 = __half22float2(acc2), f3 = __half22float2(acc3);
    float r[8] = { f0.x * inv, f0.y * inv, f1.x * inv, f1.y * inv,
                   f2.x * inv, f2.y * inv, f3.x * inv, f3.y * inv };
    int cb = blk * 32 + c_loc;
#pragma unroll
    for (int j = 0; j < 8; ++j) {
        int c = cb + j;
        float v = r[j] + bias[c];
        if (BN) {
            v = (v - mean[c]) * rsqrtf(var[c] + 1e-5f) * gamma[c] + beta[c];
            v = v > 0.f ? v : expm1f(v);   // ELU
        }
        r[j] = v;
    }
    if (OUTH) {
        short8 o;
#pragma unroll
        for (int j = 0; j < 8; ++j) o[j] = f2h(r[j]);
        *(short8*)((short*)outp + (size_t)n * HC + cb) = o;
    } else {
        float* op = (float*)outp + (size_t)n * HC + cb;
        *(float4*)op       = make_float4(r[0], r[1], r[2], r[3]);
        *(float4*)(op + 4) = make_float4(r[4], r[5], r[6], r[7]);
    }
}

extern "C" void kernel_launch(void* const* d_in, const int* in_sizes, int n_in,
                              void* d_out, int out_size, void* d_ws, size_t ws_size,
                              hipStream_t stream)
{
    const float* x   = (const float*)d_in[0];
    const int*   ei  = (const int*)d_in[1];
    const float* W1  = (const float*)d_in[2];
    const float* as1 = (const float*)d_in[3];
    const float* ad1 = (const float*)d_in[4];
    const float* b1  = (const float*)d_in[5];
    const float* g1  = (const float*)d_in[6];
    const float* be1 = (const float*)d_in[7];
    const float* mn1 = (const float*)d_in[8];
    const float* vr1 = (const float*)d_in[9];
    const float* W2  = (const float*)d_in[10];
    const float* as2 = (const float*)d_in[11];
    const float* ad2 = (const float*)d_in[12];
    const float* b2  = (const float*)d_in[13];
    const float* g2  = (const float*)d_in[14];
    const float* be2 = (const float*)d_in[15];
    const float* mn2 = (const float*)d_in[16];
    const float* vr2 = (const float*)d_in[17];
    const float* W3  = (const float*)d_in[18];
    const float* as3 = (const float*)d_in[19];
    const float* ad3 = (const float*)d_in[20];
    const float* b3  = (const float*)d_in[21];

    char* p = (char*)d_ws;
    short* hbuf    = (short*)p; p += (size_t)N_NODES * 256 * 2;     // 25.6 MB (slice-major h, fp16)
    short* obuf    = (short*)p; p += (size_t)N_NODES * 256 * 2;     // 25.6 MB (row-major layer out, fp16)
    short* wtbuf   = (short*)p; p += (size_t)131072 * 2;            // 256 KB (wt1|wt2|wt3)
    float* als     = (float*)p; p += (size_t)N_NODES * 8 * 4;       // head-major [h][n]
    float* ald     = (float*)p; p += (size_t)N_NODES * 8 * 4;
    int*   row_ptr = (int*)p;   p += (size_t)(N_NODES + 1) * 4;
    int*   col     = (int*)p;   p += (size_t)E_TOT * 4;
    int*   dstv    = (int*)p;   p += (size_t)E_TOT * 4;
    int*   deg     = (int*)p;   p += (size_t)N_NODES * 4;
    int*   cursor  = (int*)p;   p += (size_t)N_NODES * 4;
    int*   bsum    = (int*)p;   p += 64 * 4;
    int*   bpre    = (int*)p;   p += 64 * 4;

    short* wt1 = wtbuf;           // [256][128]
    short* wt2 = wtbuf + 32768;   // [256][256]
    short* wt3 = wtbuf + 98304;   // [128][256]

    float* out = (float*)d_out;

    // ----- CSR build + weight casts -----
    hipMemsetAsync(deg, 0, (size_t)N_NODES * 4, stream);
    deg_kernel<<<(E_TOT + 255) / 256, 256, 0, stream>>>(ei, deg);
    scan_p1<<<SNB, 256, 0, stream>>>(deg, bsum);
    scan_p2<<<1, 64, 0, stream>>>(bsum, bpre, row_ptr);
    scan_p3<<<SNB, 256, 0, stream>>>(deg, bpre, row_ptr, cursor);
    fill_kernel<<<(E_TOT + 255) / 256, 256, 0, stream>>>(ei, cursor, col, dstv);
    wtcast_all<<<(131072 + 255) / 256, 256, 0, stream>>>(W1, W2, W3, wtbuf);

    const int nh8 = N_NODES * 8;

    // ----- layer 1: GAT(128 -> 8x32) + BN + ELU (fp32 x cast in GEMM staging) -----
    gemm_f16<true><<<dim3(2, (N_NODES + 127) / 128), 256, 0, stream>>>(x, wt1, hbuf, N_NODES, 256, 128);
    logits_blk<8, 1><<<(nh8 + 255) / 256, 256, 0, stream>>>(hbuf, as1, ad1, als, ald);
    gat_gather_lds<256, 8, true, true><<<BPG * 8, 256, 0, stream>>>(
        row_ptr, col, dstv, hbuf, als, ald, b1, g1, be1, mn1, vr1, obuf);

    // ----- layer 2: GAT(256 -> 8x32) + BN + ELU -----
    gemm_f16<false><<<dim3(2, (N_NODES + 127) / 128), 256, 0, stream>>>(obuf, wt2, hbuf, N_NODES, 256, 256);
    logits_blk<8, 1><<<(nh8 + 255) / 256, 256, 0, stream>>>(hbuf, as2, ad2, als, ald);
    gat_gather_lds<256, 8, true, true><<<BPG * 8, 256, 0, stream>>>(
        row_ptr, col, dstv, hbuf, als, ald, b2, g2, be2, mn2, vr2, obuf);

    // ----- layer 3: GAT(256 -> 1x128), heads=1 (mean == identity) -----
    gemm_f16<false><<<dim3(1, (N_NODES + 127) / 128), 256, 0, stream>>>(obuf, wt3, hbuf, N_NODES, 128, 256);
    logits_blk<1, 4><<<(N_NODES + 255) / 256, 256, 0, stream>>>(hbuf, as3, ad3, als, ald);
    gat_gather_lds<128, 1, false, false><<<BPG * 4, 256, 0, stream>>>(
        row_ptr, col, dstv, hbuf, als, ald, b3, nullptr, nullptr, nullptr, nullptr, out);
}

// Round 14
// 511.756 us; speedup vs baseline: 1.1403x; 1.0291x over previous
//
#include <hip/hip_runtime.h>
#include <hip/hip_fp16.h>
#include <math.h>

#define N_NODES 50000
#define E_ORIG  800000
#define E_TOT   850000   // + self loops
#define SNB     49       // scan blocks: 49 * 1024 >= N_NODES
#define BPG     782      // gather node-blocks per slice: 782 * 64 >= N_NODES
#define CAP     1280     // LDS edge-window: mean block edge-count 1088, +5.8 sigma
#define WSCALE  0.00390625f   // 2^-8: keeps half2(w) < fp16 max up to logit ~16.6
#define WUNSCALE 256.0f

typedef __attribute__((ext_vector_type(8))) short    short8;
typedef __attribute__((ext_vector_type(8))) _Float16 half8;
typedef __attribute__((ext_vector_type(4))) float    f32x4;

__device__ __forceinline__ short f2h(float f) {             // fp32 -> fp16 RNE
    _Float16 h = (_Float16)f;
    return __builtin_bit_cast(short, h);
}
__device__ __forceinline__ float h2f(short s) {
    _Float16 h = __builtin_bit_cast(_Float16, s);
    return (float)h;
}

// ---------------- fp16 MFMA GEMM + optional fused logits epilogue ----------------
// C_t[blk][m][32] slice-major. DOLOG (layers 1/2): a wave's 64 columns = exactly 2 heads,
// so al_s/al_d per row = in-register partials + 16-lane shfl_xor butterfly; computed from
// fp32 acc (pre-quantization - closer to reference than reading back fp16 h).
template<bool AF32, bool DOLOG>
__global__ __launch_bounds__(256) void gemm_f16(const void* __restrict__ Av,
                                                const short* __restrict__ Wt,   // W^T [N][K] fp16
                                                short* __restrict__ C,          // [N/32][N_NODES][32]
                                                int M, int N, int K,
                                                const float* __restrict__ a_src,
                                                const float* __restrict__ a_dst,
                                                float* __restrict__ al_s,
                                                float* __restrict__ al_d)
{
    __shared__ short sA[128][40];
    __shared__ short sB[128][40];
    const int t    = threadIdx.x;
    const int wave = t >> 6, lane = t & 63;
    const int quad = lane >> 4, mrow = lane & 15;
    const int m0 = blockIdx.y * 128, n0 = blockIdx.x * 128;
    const int wm = (wave & 1) * 64, wn = (wave >> 1) * 64;

    f32x4 acc[4][4] = {};

    const int ra = t >> 2, ka = (t & 3) << 3;   // A: 2 passes of 64 rows, 8 elems each
    const int nb = t >> 1, kb = (t & 1) << 4;   // B: 128 rows, 16 shorts per thread

    for (int k0 = 0; k0 < K; k0 += 32) {
#pragma unroll
        for (int rr = 0; rr < 2; ++rr) {
            int row = ra + rr * 64;
            int gm = m0 + row;
            if (AF32) {
                const float* Af = (const float*)Av;
                float4 v0 = make_float4(0.f, 0.f, 0.f, 0.f), v1 = v0;
                if (gm < M) {
                    const float* src = Af + (size_t)gm * K + k0 + ka;
                    v0 = *(const float4*)src;
                    v1 = *(const float4*)(src + 4);
                }
                sA[row][ka + 0] = f2h(v0.x); sA[row][ka + 1] = f2h(v0.y);
                sA[row][ka + 2] = f2h(v0.z); sA[row][ka + 3] = f2h(v0.w);
                sA[row][ka + 4] = f2h(v1.x); sA[row][ka + 5] = f2h(v1.y);
                sA[row][ka + 6] = f2h(v1.z); sA[row][ka + 7] = f2h(v1.w);
            } else {
                const short* Ab = (const short*)Av;
                int4 v = {0, 0, 0, 0};
                if (gm < M) v = *(const int4*)(Ab + (size_t)gm * K + k0 + ka);
                *(int4*)&sA[row][ka] = v;
            }
        }
        {
            const int4* src = (const int4*)(Wt + (size_t)(n0 + nb) * K + k0 + kb);
            *(int4*)&sB[nb][kb]     = src[0];
            *(int4*)&sB[nb][kb + 8] = src[1];
        }
        __syncthreads();
        short8 af[4], bfr[4];
#pragma unroll
        for (int mi = 0; mi < 4; ++mi)
            af[mi] = *(const short8*)&sA[wm + mi * 16 + mrow][quad * 8];
#pragma unroll
        for (int ni = 0; ni < 4; ++ni)
            bfr[ni] = *(const short8*)&sB[wn + ni * 16 + mrow][quad * 8];
#pragma unroll
        for (int mi = 0; mi < 4; ++mi)
#pragma unroll
            for (int ni = 0; ni < 4; ++ni)
                acc[mi][ni] = __builtin_amdgcn_mfma_f32_16x16x32_f16(
                    __builtin_bit_cast(half8, af[mi]),
                    __builtin_bit_cast(half8, bfr[ni]), acc[mi][ni], 0, 0, 0);
        __syncthreads();
    }
    // C/D layout: col = lane&15, row = quad*4 + reg; write slice-major
#pragma unroll
    for (int mi = 0; mi < 4; ++mi) {
#pragma unroll
        for (int ni = 0; ni < 4; ++ni) {
            int gn = n0 + wn + ni * 16 + mrow;
            size_t sbase = ((size_t)(gn >> 5) * N_NODES) * 32 + (gn & 31);
            int gmb = m0 + wm + mi * 16 + quad * 4;
#pragma unroll
            for (int r = 0; r < 4; ++r) {
                int gm = gmb + r;
                if (gm < M) C[sbase + (size_t)gm * 32] = f2h(acc[mi][ni][r]);
            }
        }
    }
    if (DOLOG) {
        float as_c[4], ad_c[4];
#pragma unroll
        for (int ni = 0; ni < 4; ++ni) {
            int gn = n0 + wn + ni * 16 + mrow;
            as_c[ni] = a_src[gn];
            ad_c[ni] = a_dst[gn];
        }
        int h0 = (n0 + wn) >> 5;          // wave's 2 heads: h0, h0+1
#pragma unroll
        for (int mi = 0; mi < 4; ++mi) {
#pragma unroll
            for (int r = 0; r < 4; ++r) {
                float s0 = acc[mi][0][r] * as_c[0] + acc[mi][1][r] * as_c[1];
                float s1 = acc[mi][2][r] * as_c[2] + acc[mi][3][r] * as_c[3];
                float d0 = acc[mi][0][r] * ad_c[0] + acc[mi][1][r] * ad_c[1];
                float d1 = acc[mi][2][r] * ad_c[2] + acc[mi][3][r] * ad_c[3];
#pragma unroll
                for (int off = 1; off < 16; off <<= 1) {   // reduce over 16 cols (mrow)
                    s0 += __shfl_xor(s0, off, 16);
                    s1 += __shfl_xor(s1, off, 16);
                    d0 += __shfl_xor(d0, off, 16);
                    d1 += __shfl_xor(d1, off, 16);
                }
                if (mrow == 0) {
                    int gm = m0 + wm + mi * 16 + quad * 4 + r;
                    if (gm < M) {
                        al_s[(size_t)h0 * N_NODES + gm]       = s0;
                        al_s[(size_t)(h0 + 1) * N_NODES + gm] = s1;
                        al_d[(size_t)h0 * N_NODES + gm]       = d0;
                        al_d[(size_t)(h0 + 1) * N_NODES + gm] = d1;
                    }
                }
            }
        }
    }
}

// ---------------- W^T casts, one launch ----------------
__global__ void wtcast_all(const float* __restrict__ W1, const float* __restrict__ W2,
                           const float* __restrict__ W3, short* __restrict__ wt)
{
    int i = blockIdx.x * blockDim.x + threadIdx.x;
    if (i < 32768) {                       // W1: K=128, N=256
        int n = i / 128, k = i % 128;
        wt[i] = f2h(W1[(size_t)k * 256 + n]);
    } else if (i < 98304) {                // W2: K=256, N=256
        int j = i - 32768;
        int n = j / 256, k = j % 256;
        wt[i] = f2h(W2[(size_t)k * 256 + n]);
    } else if (i < 131072) {               // W3: K=256, N=128
        int j = i - 98304;
        int n = j / 256, k = j % 256;
        wt[i] = f2h(W3[(size_t)k * 128 + n]);
    }
}

// ---------------- attention logits (layer 3 only: head spans 2 waves in GEMM) ----------------
template<int H, int BPH>
__global__ void logits_blk(const short* __restrict__ ht,
                           const float* __restrict__ a_src,
                           const float* __restrict__ a_dst,
                           float* __restrict__ al_s, float* __restrict__ al_d)
{
    int i = blockIdx.x * blockDim.x + threadIdx.x;
    if (i >= N_NODES * H) return;
    int n = i / H, hh = i % H;
    float ss = 0.f, sd = 0.f;
#pragma unroll
    for (int b = 0; b < BPH; ++b) {
        int blk = hh * BPH + b;
        const short* hp = ht + ((size_t)blk * N_NODES + n) * 32;
        const float* as = a_src + blk * 32;
        const float* ad = a_dst + blk * 32;
#pragma unroll
        for (int c8 = 0; c8 < 32; c8 += 8) {
            short8 hv = *(const short8*)(hp + c8);
#pragma unroll
            for (int j = 0; j < 8; ++j) {
                float v = h2f(hv[j]);
                ss = fmaf(v, as[c8 + j], ss);
                sd = fmaf(v, ad[c8 + j], sd);
            }
        }
    }
    al_s[(size_t)hh * N_NODES + n] = ss;
    al_d[(size_t)hh * N_NODES + n] = sd;
}

// ---------------- CSR build ----------------
__global__ void deg_kernel(const int* __restrict__ ei, int* __restrict__ deg)
{
    int e = blockIdx.x * blockDim.x + threadIdx.x;
    if (e >= E_TOT) return;
    int d = (e < E_ORIG) ? ei[E_ORIG + e] : e - E_ORIG;
    atomicAdd(&deg[d], 1);
}

__global__ __launch_bounds__(256) void scan_p1(const int* __restrict__ deg, int* __restrict__ bsum)
{
    __shared__ int wsum[4];
    int t = threadIdx.x;
    int base = blockIdx.x * 1024 + t * 4;
    int s = 0;
    if (base + 3 < N_NODES) {
        int4 v = *(const int4*)(deg + base);
        s = v.x + v.y + v.z + v.w;
    } else if (base < N_NODES) {
        for (int j = 0; j < 4 && base + j < N_NODES; ++j) s += deg[base + j];
    }
#pragma unroll
    for (int d = 32; d; d >>= 1) s += __shfl_down(s, d);
    if ((t & 63) == 0) wsum[t >> 6] = s;
    __syncthreads();
    if (t == 0) bsum[blockIdx.x] = wsum[0] + wsum[1] + wsum[2] + wsum[3];
}

__global__ void scan_p2(const int* __restrict__ bsum, int* __restrict__ bpre,
                        int* __restrict__ row_ptr)
{
    int t = threadIdx.x;   // 64 threads
    int v = (t < SNB) ? bsum[t] : 0;
    int inc = v;
#pragma unroll
    for (int d = 1; d < 64; d <<= 1) {
        int u = __shfl_up(inc, d);
        if (t >= d) inc += u;
    }
    if (t < SNB) bpre[t] = inc - v;
    if (t == SNB - 1) row_ptr[N_NODES] = inc;
}

__global__ __launch_bounds__(256) void scan_p3(const int* __restrict__ deg,
                                               const int* __restrict__ bpre,
                                               int* __restrict__ row_ptr,
                                               int* __restrict__ cursor)
{
    __shared__ int tsum[256];
    int t = threadIdx.x;
    int base = blockIdx.x * 1024 + t * 4;
    int d0 = 0, d1 = 0, d2 = 0, d3 = 0;
    if (base + 3 < N_NODES) {
        int4 v = *(const int4*)(deg + base);
        d0 = v.x; d1 = v.y; d2 = v.z; d3 = v.w;
    } else if (base < N_NODES) {
        d0 = deg[base];
        if (base + 1 < N_NODES) d1 = deg[base + 1];
        if (base + 2 < N_NODES) d2 = deg[base + 2];
    }
    int s = d0 + d1 + d2 + d3;
    tsum[t] = s;
    __syncthreads();
    for (int off = 1; off < 256; off <<= 1) {
        int u = (t >= off) ? tsum[t - off] : 0;
        __syncthreads();
        tsum[t] += u;
        __syncthreads();
    }
    int run = bpre[blockIdx.x] + tsum[t] - s;
    if (base < N_NODES)     { row_ptr[base]     = run; cursor[base]     = run; run += d0; }
    if (base + 1 < N_NODES) { row_ptr[base + 1] = run; cursor[base + 1] = run; run += d1; }
    if (base + 2 < N_NODES) { row_ptr[base + 2] = run; cursor[base + 2] = run; run += d2; }
    if (base + 3 < N_NODES) { row_ptr[base + 3] = run; cursor[base + 3] = run; }
}

__global__ void fill_kernel(const int* __restrict__ ei, int* __restrict__ cursor,
                            int* __restrict__ col, int* __restrict__ dstv)
{
    int e = blockIdx.x * blockDim.x + threadIdx.x;
    if (e >= E_TOT) return;
    int s, d;
    if (e < E_ORIG) { s = ei[e]; d = ei[E_ORIG + e]; } else { s = d = e - E_ORIG; }
    int pos = atomicAdd(&cursor[d], 1);
    col[pos] = s;
    dstv[pos] = d;
}

// ---------------- slice-blocked gather, XCD-pinned, int2-staged edges, half2 fma ----------------
// Staged entry: {col, half2(w*2^-8)}. den accumulated in half2 (both halves carry the full
// sum; rel err ~1e-3 - inside tolerance). 8-edge unroll: 8 h-loads in flight per iteration.
template<int HC, int H, bool BN, bool OUTH>
__global__ __launch_bounds__(256) void gat_gather_lds(const int* __restrict__ row_ptr,
                                                      const int* __restrict__ col,
                                                      const int* __restrict__ dstv,
                                                      const short* __restrict__ ht,
                                                      const float* __restrict__ al_s,
                                                      const float* __restrict__ al_d,
                                                      const float* __restrict__ bias,
                                                      const float* __restrict__ gamma,
                                                      const float* __restrict__ beta,
                                                      const float* __restrict__ mean,
                                                      const float* __restrict__ var,
                                                      void* __restrict__ outp)
{
    constexpr int NBLK = HC / 32;
    __shared__ int2 s_cw[CAP];           // {src, half2(w*2^-8)}
    int blk  = blockIdx.x % NBLK;        // slice id == XCD id (mod 8)
    int nb   = blockIdx.x / NBLK;
    int t    = threadIdx.x;
    int n    = nb * 64 + (t >> 2);
    int lane = t & 3;
    int head = (blk * H) / NBLK;
    int c_loc = lane * 8;
    const short* hb  = ht + (size_t)blk * N_NODES * 32 + c_loc;
    const float* als = al_s + (size_t)head * N_NODES;
    const float* ald = al_d + (size_t)head * N_NODES;

    int n0 = nb * 64;
    int n1 = n0 + 64; if (n1 > N_NODES) n1 = N_NODES;
    int eb = row_ptr[n0], ee = row_ptr[n1];   // block-uniform window bounds

    int mybeg = 0, myend = 0;
    if (n < N_NODES) { mybeg = row_ptr[n]; myend = row_ptr[n + 1]; }

    __half2 acc0 = __float2half2_rn(0.f), acc1 = acc0, acc2 = acc0, acc3 = acc0;
    __half2 den2 = __float2half2_rn(0.f);
#define ACC(hv, w2) { \
        acc0 = __hfma2(w2, __builtin_bit_cast(__half2, hv.x), acc0); \
        acc1 = __hfma2(w2, __builtin_bit_cast(__half2, hv.y), acc1); \
        acc2 = __hfma2(w2, __builtin_bit_cast(__half2, hv.z), acc2); \
        acc3 = __hfma2(w2, __builtin_bit_cast(__half2, hv.w), acc3); }
#define STEP1(cw, hvar) \
        int4 hvar = *(const int4*)(hb + (size_t)(cw).x * 32);

    for (int w0 = eb; w0 < ee; w0 += CAP) {
        int w1 = w0 + CAP; if (w1 > ee) w1 = ee;
        // ---- cooperative staging (coalesced; one thread per edge) ----
        for (int i = w0 + t; i < w1; i += 256) {
            int c = col[i], d = dstv[i];
            float v = als[c] + ald[d];
            v = v > 0.f ? v : 0.2f * v;
            __half2 w2 = __float2half2_rn(__expf(v) * WSCALE);
            s_cw[i - w0] = make_int2(c, __builtin_bit_cast(int, w2));
        }
        __syncthreads();
        // ---- per-node accumulate from LDS ----
        int lo = mybeg > w0 ? mybeg : w0;
        int hi = myend < w1 ? myend : w1;
        int e = lo;
        for (; e + 7 < hi; e += 8) {
            int2 cw0 = s_cw[e - w0],     cw1 = s_cw[e - w0 + 1];
            int2 cw2 = s_cw[e - w0 + 2], cw3 = s_cw[e - w0 + 3];
            int2 cw4 = s_cw[e - w0 + 4], cw5 = s_cw[e - w0 + 5];
            int2 cw6 = s_cw[e - w0 + 6], cw7 = s_cw[e - w0 + 7];
            STEP1(cw0, h0) STEP1(cw1, h1) STEP1(cw2, h2) STEP1(cw3, h3)
            STEP1(cw4, h4) STEP1(cw5, h5) STEP1(cw6, h6) STEP1(cw7, h7)
            __half2 w20 = __builtin_bit_cast(__half2, cw0.y), w21 = __builtin_bit_cast(__half2, cw1.y);
            __half2 w22 = __builtin_bit_cast(__half2, cw2.y), w23 = __builtin_bit_cast(__half2, cw3.y);
            __half2 w24 = __builtin_bit_cast(__half2, cw4.y), w25 = __builtin_bit_cast(__half2, cw5.y);
            __half2 w26 = __builtin_bit_cast(__half2, cw6.y), w27 = __builtin_bit_cast(__half2, cw7.y);
            den2 = __hadd2(den2, __hadd2(__hadd2(w20, w21), __hadd2(w22, w23)));
            den2 = __hadd2(den2, __hadd2(__hadd2(w24, w25), __hadd2(w26, w27)));
            ACC(h0, w20); ACC(h1, w21); ACC(h2, w22); ACC(h3, w23);
            ACC(h4, w24); ACC(h5, w25); ACC(h6, w26); ACC(h7, w27);
        }
        for (; e + 3 < hi; e += 4) {
            int2 cw0 = s_cw[e - w0],     cw1 = s_cw[e - w0 + 1];
            int2 cw2 = s_cw[e - w0 + 2], cw3 = s_cw[e - w0 + 3];
            STEP1(cw0, h0) STEP1(cw1, h1) STEP1(cw2, h2) STEP1(cw3, h3)
            __half2 w20 = __builtin_bit_cast(__half2, cw0.y), w21 = __builtin_bit_cast(__half2, cw1.y);
            __half2 w22 = __builtin_bit_cast(__half2, cw2.y), w23 = __builtin_bit_cast(__half2, cw3.y);
            den2 = __hadd2(den2, __hadd2(__hadd2(w20, w21), __hadd2(w22, w23)));
            ACC(h0, w20); ACC(h1, w21); ACC(h2, w22); ACC(h3, w23);
        }
        for (; e < hi; ++e) {
            int2 cw = s_cw[e - w0];
            STEP1(cw, h0)
            __half2 w2 = __builtin_bit_cast(__half2, cw.y);
            den2 = __hadd2(den2, w2);
            ACC(h0, w2);
        }
        __syncthreads();
    }
#undef ACC
#undef STEP1
    if (n >= N_NODES) return;
    float inv = 1.0f / __low2float(den2);    // WSCALE cancels: acc and den both carry 2^-8
    float2 f0 = __half22float2(acc0), f1 = __half22float2(acc1);
    float2 f2 = __half22float2(acc2), f3 = __half22float2(acc3);
    float r[8] = { f0.x * inv, f0.y * inv, f1.x * inv, f1.y * inv,
                   f2.x * inv, f2.y * inv, f3.x * inv, f3.y * inv };
    int cb = blk * 32 + c_loc;
#pragma unroll
    for (int j = 0; j < 8; ++j) {
        int c = cb + j;
        float v = r[j] + bias[c];
        if (BN) {
            v = (v - mean[c]) * rsqrtf(var[c] + 1e-5f) * gamma[c] + beta[c];
            v = v > 0.f ? v : expm1f(v);   // ELU
        }
        r[j] = v;
    }
    if (OUTH) {
        short8 o;
#pragma unroll
        for (int j = 0; j < 8; ++j) o[j] = f2h(r[j]);
        *(short8*)((short*)outp + (size_t)n * HC + cb) = o;
    } else {
        float* op = (float*)outp + (size_t)n * HC + cb;
        *(float4*)op       = make_float4(r[0], r[1], r[2], r[3]);
        *(float4*)(op + 4) = make_float4(r[4], r[5], r[6], r[7]);
    }
}

extern "C" void kernel_launch(void* const* d_in, const int* in_sizes, int n_in,
                              void* d_out, int out_size, void* d_ws, size_t ws_size,
                              hipStream_t stream)
{
    const float* x   = (const float*)d_in[0];
    const int*   ei  = (const int*)d_in[1];
    const float* W1  = (const float*)d_in[2];
    const float* as1 = (const float*)d_in[3];
    const float* ad1 = (const float*)d_in[4];
    const float* b1  = (const float*)d_in[5];
    const float* g1  = (const float*)d_in[6];
    const float* be1 = (const float*)d_in[7];
    const float* mn1 = (const float*)d_in[8];
    const float* vr1 = (const float*)d_in[9];
    const float* W2  = (const float*)d_in[10];
    const float* as2 = (const float*)d_in[11];
    const float* ad2 = (const float*)d_in[12];
    const float* b2  = (const float*)d_in[13];
    const float* g2  = (const float*)d_in[14];
    const float* be2 = (const float*)d_in[15];
    const float* mn2 = (const float*)d_in[16];
    const float* vr2 = (const float*)d_in[17];
    const float* W3  = (const float*)d_in[18];
    const float* as3 = (const float*)d_in[19];
    const float* ad3 = (const float*)d_in[20];
    const float* b3  = (const float*)d_in[21];

    char* p = (char*)d_ws;
    short* hbuf    = (short*)p; p += (size_t)N_NODES * 256 * 2;     // 25.6 MB (slice-major h, fp16)
    short* obuf    = (short*)p; p += (size_t)N_NODES * 256 * 2;     // 25.6 MB (row-major layer out, fp16)
    short* wtbuf   = (short*)p; p += (size_t)131072 * 2;            // 256 KB (wt1|wt2|wt3)
    float* als     = (float*)p; p += (size_t)N_NODES * 8 * 4;       // head-major [h][n]
    float* ald     = (float*)p; p += (size_t)N_NODES * 8 * 4;
    int*   row_ptr = (int*)p;   p += (size_t)(N_NODES + 1) * 4;
    int*   col     = (int*)p;   p += (size_t)E_TOT * 4;
    int*   dstv    = (int*)p;   p += (size_t)E_TOT * 4;
    int*   deg     = (int*)p;   p += (size_t)N_NODES * 4;
    int*   cursor  = (int*)p;   p += (size_t)N_NODES * 4;
    int*   bsum    = (int*)p;   p += 64 * 4;
    int*   bpre    = (int*)p;   p += 64 * 4;

    short* wt1 = wtbuf;           // [256][128]
    short* wt2 = wtbuf + 32768;   // [256][256]
    short* wt3 = wtbuf + 98304;   // [128][256]

    float* out = (float*)d_out;

    // ----- CSR build + weight casts -----
    hipMemsetAsync(deg, 0, (size_t)N_NODES * 4, stream);
    deg_kernel<<<(E_TOT + 255) / 256, 256, 0, stream>>>(ei, deg);
    scan_p1<<<SNB, 256, 0, stream>>>(deg, bsum);
    scan_p2<<<1, 64, 0, stream>>>(bsum, bpre, row_ptr);
    scan_p3<<<SNB, 256, 0, stream>>>(deg, bpre, row_ptr, cursor);
    fill_kernel<<<(E_TOT + 255) / 256, 256, 0, stream>>>(ei, cursor, col, dstv);
    wtcast_all<<<(131072 + 255) / 256, 256, 0, stream>>>(W1, W2, W3, wtbuf);

    // ----- layer 1: GAT(128 -> 8x32) + BN + ELU (x cast + logits fused into GEMM) -----
    gemm_f16<true, true><<<dim3(2, (N_NODES + 127) / 128), 256, 0, stream>>>(
        x, wt1, hbuf, N_NODES, 256, 128, as1, ad1, als, ald);
    gat_gather_lds<256, 8, true, true><<<BPG * 8, 256, 0, stream>>>(
        row_ptr, col, dstv, hbuf, als, ald, b1, g1, be1, mn1, vr1, obuf);

    // ----- layer 2: GAT(256 -> 8x32) + BN + ELU (logits fused into GEMM) -----
    gemm_f16<false, true><<<dim3(2, (N_NODES + 127) / 128), 256, 0, stream>>>(
        obuf, wt2, hbuf, N_NODES, 256, 256, as2, ad2, als, ald);
    gat_gather_lds<256, 8, true, true><<<BPG * 8, 256, 0, stream>>>(
        row_ptr, col, dstv, hbuf, als, ald, b2, g2, be2, mn2, vr2, obuf);

    // ----- layer 3: GAT(256 -> 1x128), heads=1 (mean == identity) -----
    gemm_f16<false, false><<<dim3(1, (N_NODES + 127) / 128), 256, 0, stream>>>(
        obuf, wt3, hbuf, N_NODES, 128, 256, nullptr, nullptr, nullptr, nullptr);
    logits_blk<1, 4><<<(N_NODES + 255) / 256, 256, 0, stream>>>(hbuf, as3, ad3, als, ald);
    gat_gather_lds<128, 1, false, false><<<BPG * 4, 256, 0, stream>>>(
        row_ptr, col, dstv, hbuf, als, ald, b3, nullptr, nullptr, nullptr, nullptr, out);
}